// Round 2
// baseline (183.960 us; speedup 1.0000x reference)
//
#include <hip/hip_runtime.h>

typedef __attribute__((ext_vector_type(4))) float f32x4;
typedef __attribute__((ext_vector_type(8))) short bf16x8;
typedef unsigned short u16;

__device__ __forceinline__ u16 f2bf(float f){
  unsigned u = __float_as_uint(f);
  u += 0x7FFFu + ((u >> 16) & 1u);
  return (u16)(u >> 16);
}

// ---------------------------------------------------------------------------
// K0: repack f32 weights into bf16 MFMA B-fragment order + expand relative
// bias into MFMA C-fragment layout (f32). Fragment (kk, nt, lane, j) holds
// W[k = kk*32 + (lane>>4)*8 + j][col = nt*16 + (lane&15)].
// ---------------------------------------------------------------------------
__global__ void repack_kernel(const float* __restrict__ qkv_w, const float* __restrict__ proj_w,
                              const float* __restrict__ w1, const float* __restrict__ w2,
                              const float* __restrict__ tbl,
                              u16* __restrict__ rq, u16* __restrict__ rp,
                              u16* __restrict__ r1, u16* __restrict__ r2,
                              float* __restrict__ be){
  const int i = blockIdx.x * 256 + threadIdx.x;          // 0 .. 65535
  const int j = i & 7, lane = (i >> 3) & 63, f = i >> 9;
  const int kr = (lane >> 4) * 8 + j;                    // k within 32-chunk
  const int c16 = lane & 15;
  if (i < 49152){ int nt = f % 24, kk = f / 24; rq[i] = f2bf(qkv_w[(kk*32 + kr)*384 + nt*16 + c16]); }
  if (i < 16384){ int nt = f & 7,  kk = f >> 3; rp[i] = f2bf(proj_w[(kk*32 + kr)*128 + nt*16 + c16]); }
  if (i < 65536){ int nt = f & 31, kk = f >> 5; r1[i] = f2bf(w1[(kk*32 + kr)*512 + nt*16 + c16]); }
  if (i < 65536){ int nt = f & 7,  kk = f >> 3; r2[i] = f2bf(w2[(kk*32 + kr)*128 + nt*16 + c16]); }
  if (i < 16384){
    int rg = i & 3, ln = (i >> 2) & 63, g = i >> 8;
    int nt = g & 3, mt = (g >> 2) & 3, h = g >> 4;
    int row = mt*16 + (ln >> 4)*4 + rg, col = nt*16 + (ln & 15);  // (q_tok, k_tok)
    int rel = ((row >> 3) - (col >> 3) + 7) * 15 + ((row & 7) - (col & 7) + 7);
    be[i] = tbl[rel*4 + h];
  }
}

// ---------------------------------------------------------------------------
// K1: per-window fused LN1 + QKV + attention(+bias,softmax) + proj + residual.
// Block = 256 threads (4 waves, wave == head). LDS 64 KB -> 2 blocks/CU.
// ---------------------------------------------------------------------------
__global__ __launch_bounds__(256, 2)
void attn_kernel(const float* __restrict__ x,
                 const float* __restrict__ qkv_b, const float* __restrict__ proj_b,
                 const float* __restrict__ ln1_g, const float* __restrict__ ln1_b,
                 const u16* __restrict__ rep_qkv, const u16* __restrict__ rep_proj,
                 const float* __restrict__ bias_exp,
                 float* __restrict__ msa){
  __shared__ __align__(16) u16 sA[8192];    // 64x128 bf16 tile: LN1'd x, later O
  __shared__ __align__(16) u16 sB[24576];   // per head (6144): Q|K|VT, P overlays Q+K; f32 proj staging at end
  const int tid = threadIdx.x, lane = tid & 63, wid = tid >> 6;
  const int wdw = blockIdx.x;
  const int bb = wdw >> 6, ihb = (wdw >> 3) & 7, iwb = wdw & 7;
  const float* xb = x + (size_t)bb * 4096 * 128;
  float* mb = msa + (size_t)bb * 4096 * 128;
  const f32x4 z4 = {0.f, 0.f, 0.f, 0.f};
  const int rb = tid >> 4, cb = tid & 15, c0g = cb * 8;
  float xs[4][8];                           // this thread's window elements (reused for residual)

  // ---- phase 1: load window + LN1 -> sA (bf16, swizzled) ----
  {
    float g8[8], b8[8];
    *(f32x4*)&g8[0] = *(const f32x4*)(ln1_g + c0g);
    *(f32x4*)&g8[4] = *(const f32x4*)(ln1_g + c0g + 4);
    *(f32x4*)&b8[0] = *(const f32x4*)(ln1_b + c0g);
    *(f32x4*)&b8[4] = *(const f32x4*)(ln1_b + c0g + 4);
    #pragma unroll
    for (int it = 0; it < 4; ++it){
      const int r = it * 16 + rb;
      const int pix = ((r >> 3) * 8 + ihb) * 64 + (r & 7) * 8 + iwb;
      *(f32x4*)&xs[it][0] = *(const f32x4*)(xb + (size_t)pix * 128 + c0g);
      *(f32x4*)&xs[it][4] = *(const f32x4*)(xb + (size_t)pix * 128 + c0g + 4);
      float s = 0.f, sq = 0.f;
      #pragma unroll
      for (int j = 0; j < 8; ++j){ s += xs[it][j]; sq += xs[it][j]*xs[it][j]; }
      #pragma unroll
      for (int m = 1; m < 16; m <<= 1){ s += __shfl_xor(s, m); sq += __shfl_xor(sq, m); }
      const float mean = s * (1.f/128.f);
      const float rs = rsqrtf(sq * (1.f/128.f) - mean*mean + 1e-5f);
      bf16x8 o;
      #pragma unroll
      for (int j = 0; j < 8; ++j)
        o[j] = (short)f2bf((xs[it][j]-mean)*rs*g8[j] + b8[j]);
      *(bf16x8*)&sA[r*128 + (c0g ^ ((r & 7) << 3))] = o;
    }
  }
  __syncthreads();

  const int r15 = lane & 15, kg = lane >> 4;
  const int hbase = wid * 6144;

  // ---- phase 2: QKV = LN1(x) @ W_h (64x96), wave = head ----
  {
    f32x4 acc[4][6];
    #pragma unroll
    for (int mt = 0; mt < 4; ++mt)
      #pragma unroll
      for (int nt = 0; nt < 6; ++nt) acc[mt][nt] = z4;
    #pragma unroll
    for (int kk = 0; kk < 4; ++kk){
      bf16x8 aF[4], bF[6];
      const int c0 = kk*32 + kg*8;
      #pragma unroll
      for (int mt = 0; mt < 4; ++mt){
        const int row = mt*16 + r15;
        aF[mt] = *(const bf16x8*)&sA[row*128 + (c0 ^ ((row & 7) << 3))];
      }
      #pragma unroll
      for (int nt = 0; nt < 6; ++nt)
        bF[nt] = *(const bf16x8*)(rep_qkv + (size_t)((kk*24 + wid*6 + nt)*64 + lane)*8);
      #pragma unroll
      for (int mt = 0; mt < 4; ++mt)
        #pragma unroll
        for (int nt = 0; nt < 6; ++nt)
          acc[mt][nt] = __builtin_amdgcn_mfma_f32_16x16x32_bf16(aF[mt], bF[nt], acc[mt][nt], 0, 0, 0);
    }
    __syncthreads();   // all waves done reading sA (it gets reused for O)
    // store Q (pre-scaled), K, V^T (bf16) into this head's LDS region
    #pragma unroll
    for (int nt = 0; nt < 6; ++nt){
      const int cl = nt*16 + r15;          // 0..95 within head
      const int sel = cl >> 5, d = cl & 31;
      const float qb = qkv_b[wid*96 + cl];
      #pragma unroll
      for (int mt = 0; mt < 4; ++mt)
        #pragma unroll
        for (int rg = 0; rg < 4; ++rg){
          const int row = mt*16 + kg*4 + rg;
          const float v = acc[mt][nt][rg] + qb;
          if (sel == 0)      sB[hbase +        row*32 + (d ^ ((row & 3) << 3))] = f2bf(v * 0.17677669529663687f);
          else if (sel == 1) sB[hbase + 2048 + row*32 + (d ^ ((row & 3) << 3))] = f2bf(v);
          else               sB[hbase + 4096 + d*64   + (row ^ ((d & 7) << 3))] = f2bf(v);
        }
    }
  }

  // ---- phase 3: S = Q K^T + bias (bias as MFMA C-input), softmax ----
  f32x4 s4[4][4];
  {
    bf16x8 aQ[4], bK[4];
    #pragma unroll
    for (int mt = 0; mt < 4; ++mt){
      const int row = mt*16 + r15;
      aQ[mt] = *(const bf16x8*)&sB[hbase + row*32 + ((kg*8) ^ ((row & 3) << 3))];
    }
    #pragma unroll
    for (int nt = 0; nt < 4; ++nt){
      const int row = nt*16 + r15;
      bK[nt] = *(const bf16x8*)&sB[hbase + 2048 + row*32 + ((kg*8) ^ ((row & 3) << 3))];
    }
    #pragma unroll
    for (int mt = 0; mt < 4; ++mt)
      #pragma unroll
      for (int nt = 0; nt < 4; ++nt){
        f32x4 c = *(const f32x4*)(bias_exp + (size_t)(((wid*4 + mt)*4 + nt)*64 + lane)*4);
        s4[mt][nt] = __builtin_amdgcn_mfma_f32_16x16x32_bf16(aQ[mt], bK[nt], c, 0, 0, 0);
      }
  }
  #pragma unroll
  for (int mt = 0; mt < 4; ++mt)
    #pragma unroll
    for (int rg = 0; rg < 4; ++rg){
      float mx = fmaxf(fmaxf(s4[mt][0][rg], s4[mt][1][rg]), fmaxf(s4[mt][2][rg], s4[mt][3][rg]));
      #pragma unroll
      for (int m = 8; m >= 1; m >>= 1) mx = fmaxf(mx, __shfl_xor(mx, m));
      float sum = 0.f;
      #pragma unroll
      for (int nt = 0; nt < 4; ++nt){ float e = __expf(s4[mt][nt][rg] - mx); s4[mt][nt][rg] = e; sum += e; }
      #pragma unroll
      for (int m = 8; m >= 1; m >>= 1) sum += __shfl_xor(sum, m);
      const float inv = 1.f / sum;
      #pragma unroll
      for (int nt = 0; nt < 4; ++nt) s4[mt][nt][rg] *= inv;
    }
  // store P (overlays this head's Q+K region; same-wave dependency only)
  #pragma unroll
  for (int mt = 0; mt < 4; ++mt)
    #pragma unroll
    for (int nt = 0; nt < 4; ++nt)
      #pragma unroll
      for (int rg = 0; rg < 4; ++rg){
        const int row = mt*16 + kg*4 + rg, col = nt*16 + r15;
        sB[hbase + row*64 + (col ^ ((row & 7) << 3))] = f2bf(s4[mt][nt][rg]);
      }

  // ---- phase 4: O = P @ V ----
  f32x4 o[4][2];
  #pragma unroll
  for (int mt = 0; mt < 4; ++mt){ o[mt][0] = z4; o[mt][1] = z4; }
  #pragma unroll
  for (int ks = 0; ks < 2; ++ks){
    bf16x8 aP[4], bV[2];
    const int c0 = ks*32 + kg*8;
    #pragma unroll
    for (int mt = 0; mt < 4; ++mt){
      const int row = mt*16 + r15;
      aP[mt] = *(const bf16x8*)&sB[hbase + row*64 + (c0 ^ ((row & 7) << 3))];
    }
    #pragma unroll
    for (int nt = 0; nt < 2; ++nt){
      const int vr = nt*16 + r15;  // head-dim d
      bV[nt] = *(const bf16x8*)&sB[hbase + 4096 + vr*64 + (c0 ^ ((vr & 7) << 3))];
    }
    #pragma unroll
    for (int mt = 0; mt < 4; ++mt)
      #pragma unroll
      for (int nt = 0; nt < 2; ++nt)
        o[mt][nt] = __builtin_amdgcn_mfma_f32_16x16x32_bf16(aP[mt], bV[nt], o[mt][nt], 0, 0, 0);
  }
  #pragma unroll
  for (int mt = 0; mt < 4; ++mt)
    #pragma unroll
    for (int nt = 0; nt < 2; ++nt)
      #pragma unroll
      for (int rg = 0; rg < 4; ++rg){
        const int row = mt*16 + kg*4 + rg, col = wid*32 + nt*16 + r15;
        sA[row*128 + (col ^ ((row & 7) << 3))] = f2bf(o[mt][nt][rg]);
      }
  __syncthreads();   // all O written; all P/VT reads done

  // ---- phase 5: proj (wave owns 32 output cols), stage f32 into sB ----
  {
    float* sBf = (float*)sB;     // 8192 floats = 32 KB (fits in sB's 48 KB)
    f32x4 po[4][2];
    #pragma unroll
    for (int mt = 0; mt < 4; ++mt){ po[mt][0] = z4; po[mt][1] = z4; }
    #pragma unroll
    for (int kk = 0; kk < 4; ++kk){
      bf16x8 aO[4], bP[2];
      const int c0 = kk*32 + kg*8;
      #pragma unroll
      for (int mt = 0; mt < 4; ++mt){
        const int row = mt*16 + r15;
        aO[mt] = *(const bf16x8*)&sA[row*128 + (c0 ^ ((row & 7) << 3))];
      }
      #pragma unroll
      for (int nt = 0; nt < 2; ++nt)
        bP[nt] = *(const bf16x8*)(rep_proj + (size_t)((kk*8 + wid*2 + nt)*64 + lane)*8);
      #pragma unroll
      for (int mt = 0; mt < 4; ++mt)
        #pragma unroll
        for (int nt = 0; nt < 2; ++nt)
          po[mt][nt] = __builtin_amdgcn_mfma_f32_16x16x32_bf16(aO[mt], bP[nt], po[mt][nt], 0, 0, 0);
    }
    #pragma unroll
    for (int nt = 0; nt < 2; ++nt){
      const int col = wid*32 + nt*16 + r15;
      const float pb = proj_b[col];
      #pragma unroll
      for (int mt = 0; mt < 4; ++mt)
        #pragma unroll
        for (int rg = 0; rg < 4; ++rg){
          const int row = mt*16 + kg*4 + rg;
          sBf[row*128 + (col ^ ((row & 7) << 2))] = po[mt][nt][rg] + pb;
        }
    }
  }
  __syncthreads();

  // ---- phase 6: residual (x held in registers) + scatter to image layout ----
  {
    const float* sBf = (const float*)sB;
    #pragma unroll
    for (int it = 0; it < 4; ++it){
      const int r = it * 16 + rb;
      const int pix = ((r >> 3) * 8 + ihb) * 64 + (r & 7) * 8 + iwb;
      const int m = (r & 7) << 2;
      f32x4 p0 = *(const f32x4*)&sBf[r*128 + (c0g ^ m)];
      f32x4 p1 = *(const f32x4*)&sBf[r*128 + ((c0g + 4) ^ m)];
      f32x4 o0, o1;
      #pragma unroll
      for (int j = 0; j < 4; ++j){ o0[j] = xs[it][j] + p0[j]; o1[j] = xs[it][4+j] + p1[j]; }
      *(f32x4*)(mb + (size_t)pix * 128 + c0g)     = o0;
      *(f32x4*)(mb + (size_t)pix * 128 + c0g + 4) = o1;
    }
  }
}

// ---------------------------------------------------------------------------
// K2: LN2 + MLP (chunked over the 512 hidden dim) + residual. 64 rows/block.
// NOTE: msa and out alias (both = d_out); per-element read->write is same-thread.
// ---------------------------------------------------------------------------
__global__ __launch_bounds__(256, 2)
void mlp_kernel(const float* msa,
                const float* __restrict__ ln2_g, const float* __restrict__ ln2_b,
                const u16* __restrict__ rep_w1, const u16* __restrict__ rep_w2,
                const float* __restrict__ mlp_b1, const float* __restrict__ mlp_b2,
                float* out){
  __shared__ __align__(16) u16 sMem[16384];   // sH (8192) | sG (8192); f32 staging at end
  u16* sH = sMem;
  u16* sG = sMem + 8192;
  const int tid = threadIdx.x, lane = tid & 63, wid = tid >> 6;
  const size_t r0 = (size_t)blockIdx.x * 64;
  const f32x4 z4 = {0.f, 0.f, 0.f, 0.f};
  const int rb = tid >> 4, cb = tid & 15, c0g = cb * 8;

  // ---- LN2 -> sH (bf16, swizzled) ----
  {
    float g8[8], b8[8];
    *(f32x4*)&g8[0] = *(const f32x4*)(ln2_g + c0g);
    *(f32x4*)&g8[4] = *(const f32x4*)(ln2_g + c0g + 4);
    *(f32x4*)&b8[0] = *(const f32x4*)(ln2_b + c0g);
    *(f32x4*)&b8[4] = *(const f32x4*)(ln2_b + c0g + 4);
    #pragma unroll
    for (int it = 0; it < 4; ++it){
      const int r = it * 16 + rb;
      float fl[8];
      *(f32x4*)&fl[0] = *(const f32x4*)(msa + (r0 + r) * 128 + c0g);
      *(f32x4*)&fl[4] = *(const f32x4*)(msa + (r0 + r) * 128 + c0g + 4);
      float s = 0.f, sq = 0.f;
      #pragma unroll
      for (int j = 0; j < 8; ++j){ s += fl[j]; sq += fl[j]*fl[j]; }
      #pragma unroll
      for (int m = 1; m < 16; m <<= 1){ s += __shfl_xor(s, m); sq += __shfl_xor(sq, m); }
      const float mean = s * (1.f/128.f);
      const float rs = rsqrtf(sq * (1.f/128.f) - mean*mean + 1e-5f);
      bf16x8 o;
      #pragma unroll
      for (int j = 0; j < 8; ++j)
        o[j] = (short)f2bf((fl[j]-mean)*rs*g8[j] + b8[j]);
      *(bf16x8*)&sH[r*128 + (c0g ^ ((r & 7) << 3))] = o;
    }
  }
  __syncthreads();
  const int r15 = lane & 15, kg = lane >> 4;
  f32x4 accO[4][2];
  #pragma unroll
  for (int mt = 0; mt < 4; ++mt){ accO[mt][0] = z4; accO[mt][1] = z4; }

  #pragma unroll
  for (int c = 0; c < 4; ++c){      // 4 chunks of 128 hidden cols
    f32x4 t4[4][2];
    #pragma unroll
    for (int mt = 0; mt < 4; ++mt){ t4[mt][0] = z4; t4[mt][1] = z4; }
    #pragma unroll
    for (int kk = 0; kk < 4; ++kk){
      bf16x8 aF[4], bF[2];
      const int c0 = kk*32 + kg*8;
      #pragma unroll
      for (int mt = 0; mt < 4; ++mt){
        const int row = mt*16 + r15;
        aF[mt] = *(const bf16x8*)&sH[row*128 + (c0 ^ ((row & 7) << 3))];
      }
      #pragma unroll
      for (int nt = 0; nt < 2; ++nt)
        bF[nt] = *(const bf16x8*)(rep_w1 + (size_t)((kk*32 + c*8 + wid*2 + nt)*64 + lane)*8);
      #pragma unroll
      for (int mt = 0; mt < 4; ++mt)
        #pragma unroll
        for (int nt = 0; nt < 2; ++nt)
          t4[mt][nt] = __builtin_amdgcn_mfma_f32_16x16x32_bf16(aF[mt], bF[nt], t4[mt][nt], 0, 0, 0);
    }
    #pragma unroll
    for (int nt = 0; nt < 2; ++nt){
      const int colL = wid*32 + nt*16 + r15;
      const float b1 = mlp_b1[c*128 + colL];
      #pragma unroll
      for (int mt = 0; mt < 4; ++mt)
        #pragma unroll
        for (int rg = 0; rg < 4; ++rg){
          const int row = mt*16 + kg*4 + rg;
          const float vv = t4[mt][nt][rg] + b1;
          const float g = 0.5f * vv * (1.f + erff(vv * 0.70710678118654752f));
          sG[row*128 + (colL ^ ((row & 7) << 3))] = f2bf(g);
        }
    }
    __syncthreads();
    #pragma unroll
    for (int kk = 0; kk < 4; ++kk){
      bf16x8 aG[4], bF[2];
      const int c0 = kk*32 + kg*8;
      #pragma unroll
      for (int mt = 0; mt < 4; ++mt){
        const int row = mt*16 + r15;
        aG[mt] = *(const bf16x8*)&sG[row*128 + (c0 ^ ((row & 7) << 3))];
      }
      #pragma unroll
      for (int nt = 0; nt < 2; ++nt)
        bF[nt] = *(const bf16x8*)(rep_w2 + (size_t)(((c*4 + kk)*8 + wid*2 + nt)*64 + lane)*8);
      #pragma unroll
      for (int mt = 0; mt < 4; ++mt)
        #pragma unroll
        for (int nt = 0; nt < 2; ++nt)
          accO[mt][nt] = __builtin_amdgcn_mfma_f32_16x16x32_bf16(aG[mt], bF[nt], accO[mt][nt], 0, 0, 0);
    }
    __syncthreads();
  }

  // ---- stage mlp output (f32) into sMem, then residual + store ----
  {
    float* sMf = (float*)sMem;   // 8192 floats = 32 KB (exactly sMem)
    #pragma unroll
    for (int nt = 0; nt < 2; ++nt){
      const int col = wid*32 + nt*16 + r15;
      const float b2 = mlp_b2[col];
      #pragma unroll
      for (int mt = 0; mt < 4; ++mt)
        #pragma unroll
        for (int rg = 0; rg < 4; ++rg){
          const int row = mt*16 + kg*4 + rg;
          sMf[row*128 + (col ^ ((row & 7) << 2))] = accO[mt][nt][rg] + b2;
        }
    }
  }
  __syncthreads();
  {
    const float* sMf = (const float*)sMem;
    #pragma unroll
    for (int it = 0; it < 4; ++it){
      const int r = it * 16 + rb;
      const int m = (r & 7) << 2;
      f32x4 g0 = *(const f32x4*)&sMf[r*128 + (c0g ^ m)];
      f32x4 g1 = *(const f32x4*)&sMf[r*128 + ((c0g + 4) ^ m)];
      f32x4 m0 = *(const f32x4*)(msa + (r0 + r) * 128 + c0g);
      f32x4 m1 = *(const f32x4*)(msa + (r0 + r) * 128 + c0g + 4);
      f32x4 o0, o1;
      #pragma unroll
      for (int j = 0; j < 4; ++j){ o0[j] = m0[j] + g0[j]; o1[j] = m1[j] + g1[j]; }
      *(f32x4*)(out + (r0 + r) * 128 + c0g)     = o0;
      *(f32x4*)(out + (r0 + r) * 128 + c0g + 4) = o1;
    }
  }
}

// ---------------------------------------------------------------------------
// ws layout (bytes): rq 0..98304 | rp ..131072 | r1 ..262144 | r2 ..393216 |
// be ..458752.  msa staging lives in d_out (fully rewritten every call).
// ---------------------------------------------------------------------------
extern "C" void kernel_launch(void* const* d_in, const int* in_sizes, int n_in,
                              void* d_out, int out_size, void* d_ws, size_t ws_size,
                              hipStream_t stream){
  (void)in_sizes; (void)n_in; (void)out_size; (void)ws_size;
  const float* x      = (const float*)d_in[0];
  const float* qkv_w  = (const float*)d_in[1];
  const float* qkv_b  = (const float*)d_in[2];
  const float* proj_w = (const float*)d_in[3];
  const float* proj_b = (const float*)d_in[4];
  const float* tbl    = (const float*)d_in[5];
  const float* ln1_g  = (const float*)d_in[6];
  const float* ln1_b  = (const float*)d_in[7];
  const float* ln2_g  = (const float*)d_in[8];
  const float* ln2_b  = (const float*)d_in[9];
  const float* w1     = (const float*)d_in[10];
  const float* b1     = (const float*)d_in[11];
  const float* w2     = (const float*)d_in[12];
  const float* b2     = (const float*)d_in[13];

  char* ws = (char*)d_ws;
  u16*   rq  = (u16*)ws;
  u16*   rp  = (u16*)(ws + 98304);
  u16*   r1  = (u16*)(ws + 131072);
  u16*   r2  = (u16*)(ws + 262144);
  float* be  = (float*)(ws + 393216);
  float* msa = (float*)d_out;

  hipLaunchKernelGGL(repack_kernel, dim3(256), dim3(256), 0, stream,
                     qkv_w, proj_w, w1, w2, tbl, rq, rp, r1, r2, be);
  hipLaunchKernelGGL(attn_kernel, dim3(2048), dim3(256), 0, stream,
                     x, qkv_b, proj_b, ln1_g, ln1_b, rq, rp, be, msa);
  hipLaunchKernelGGL(mlp_kernel, dim3(2048), dim3(256), 0, stream,
                     msa, ln2_g, ln2_b, r1, r2, b1, b2, (float*)d_out);
}

// Round 3
// 131.177 us; speedup vs baseline: 1.4024x; 1.4024x over previous
//
#include <hip/hip_runtime.h>

typedef __attribute__((ext_vector_type(4))) float f32x4;
typedef __attribute__((ext_vector_type(8))) short bf16x8;
typedef __attribute__((ext_vector_type(4))) short bf16x4;
typedef unsigned short u16;

__device__ __forceinline__ u16 f2bf(float f){
  unsigned u = __float_as_uint(f);
  u += 0x7FFFu + ((u >> 16) & 1u);
  return (u16)(u >> 16);
}

// ---------------------------------------------------------------------------
// K0: repack f32 weights into bf16 MFMA fragment order + expand relative
// bias into MFMA C-fragment layout for the S^T = K·Q^T orientation
// (C row = k_token, C col = q_token).
// Fragment (kk, nt, lane, j) holds W[k = kk*32 + (lane>>4)*8 + j][nt*16 + (lane&15)].
// ---------------------------------------------------------------------------
__global__ void repack_kernel(const float* __restrict__ qkv_w, const float* __restrict__ proj_w,
                              const float* __restrict__ w1, const float* __restrict__ w2,
                              const float* __restrict__ tbl,
                              u16* __restrict__ rq, u16* __restrict__ rp,
                              u16* __restrict__ r1, u16* __restrict__ r2,
                              float* __restrict__ be){
  const int i = blockIdx.x * 256 + threadIdx.x;          // 0 .. 65535
  const int j = i & 7, lane = (i >> 3) & 63, f = i >> 9;
  const int kr = (lane >> 4) * 8 + j;                    // k within 32-chunk
  const int c16 = lane & 15;
  if (i < 49152){ int nt = f % 24, kk = f / 24; rq[i] = f2bf(qkv_w[(kk*32 + kr)*384 + nt*16 + c16]); }
  if (i < 16384){ int nt = f & 7,  kk = f >> 3; rp[i] = f2bf(proj_w[(kk*32 + kr)*128 + nt*16 + c16]); }
  if (i < 65536){ int nt = f & 31, kk = f >> 5; r1[i] = f2bf(w1[(kk*32 + kr)*512 + nt*16 + c16]); }
  if (i < 65536){ int nt = f & 7,  kk = f >> 3; r2[i] = f2bf(w2[(kk*32 + kr)*128 + nt*16 + c16]); }
  if (i < 16384){
    int rg = i & 3, ln = (i >> 2) & 63, g = i >> 8;
    int nt = g & 3, mt = (g >> 2) & 3, h = g >> 4;
    int row = mt*16 + (ln >> 4)*4 + rg;   // k_token (C row)
    int col = nt*16 + (ln & 15);          // q_token (C col)
    int rel = ((col >> 3) - (row >> 3) + 7) * 15 + ((col & 7) - (row & 7) + 7);
    be[i] = tbl[rel*4 + h];
  }
}

// ---------------------------------------------------------------------------
// K1: per-window fused LN1 + QKV + attention(+bias,softmax) + proj + residual.
// 256 threads (4 waves, wave == head). LDS 64 KB -> 2 blocks/CU.
// Q^T,K^T computed via transposed GEMM (packed b64 stores into [tok][d] tiles);
// V via normal GEMM (packed stores into V^T [d][tok]); S^T = K·Q^T so softmax-k
// is lane-major and P packs into [q][k].
// ---------------------------------------------------------------------------
__global__ __launch_bounds__(256, 2)
void attn_kernel(const float* __restrict__ x,
                 const float* __restrict__ qkv_b, const float* __restrict__ proj_b,
                 const float* __restrict__ ln1_g, const float* __restrict__ ln1_b,
                 const u16* __restrict__ rep_qkv, const u16* __restrict__ rep_proj,
                 const float* __restrict__ bias_exp,
                 float* __restrict__ msa){
  __shared__ __align__(16) u16 smem[32768];   // 64 KB
  u16* sLN = smem;                 // [64][128] bf16 LN1 tile; later sO overlays
  u16* sQ  = smem + 8192;          // [64 tok][128 d_all]
  u16* sK  = smem + 16384;         // [64 tok][128 d_all]
  u16* sV  = smem + 24576;         // V^T [128 d_all][64 tok]
  u16* sP  = smem + 8192;          // [64 q][256 k_all] overlays Q,K after sync
  u16* sO  = smem;                 // [64 q][128 ch] overlays sLN
  float* stg = (float*)(smem + 8192); // [64][128] f32 proj staging (32 KB)

  const int tid = threadIdx.x, lane = tid & 63, wid = tid >> 6;
  const int wdw = blockIdx.x;
  const int bb = wdw >> 6, ihb = (wdw >> 3) & 7, iwb = wdw & 7;
  const float* xb = x + (size_t)bb * 4096 * 128;
  float* mb = msa + (size_t)bb * 4096 * 128;
  const f32x4 z4 = {0.f, 0.f, 0.f, 0.f};
  const int rb = tid >> 4, cb = tid & 15, c0g = cb * 8;
  const int r15 = lane & 15, kg = lane >> 4;

  // ---- phase 1: load window + LN1 -> sLN (bf16, swizzled) ----
  {
    float g8[8], b8[8];
    *(f32x4*)&g8[0] = *(const f32x4*)(ln1_g + c0g);
    *(f32x4*)&g8[4] = *(const f32x4*)(ln1_g + c0g + 4);
    *(f32x4*)&b8[0] = *(const f32x4*)(ln1_b + c0g);
    *(f32x4*)&b8[4] = *(const f32x4*)(ln1_b + c0g + 4);
    #pragma unroll
    for (int it = 0; it < 4; ++it){
      const int r = it * 16 + rb;
      const int pix = ((r >> 3) * 8 + ihb) * 64 + (r & 7) * 8 + iwb;
      float fl[8];
      *(f32x4*)&fl[0] = *(const f32x4*)(xb + (size_t)pix * 128 + c0g);
      *(f32x4*)&fl[4] = *(const f32x4*)(xb + (size_t)pix * 128 + c0g + 4);
      float s = 0.f, sq = 0.f;
      #pragma unroll
      for (int j = 0; j < 8; ++j){ s += fl[j]; sq += fl[j]*fl[j]; }
      #pragma unroll
      for (int m = 1; m < 16; m <<= 1){ s += __shfl_xor(s, m); sq += __shfl_xor(sq, m); }
      const float mean = s * (1.f/128.f);
      const float rs = rsqrtf(sq * (1.f/128.f) - mean*mean + 1e-5f);
      bf16x8 o;
      #pragma unroll
      for (int j = 0; j < 8; ++j)
        o[j] = (short)f2bf((fl[j]-mean)*rs*g8[j] + b8[j]);
      *(bf16x8*)&sLN[r*128 + (c0g ^ ((r & 7) << 3))] = o;
    }
  }
  __syncthreads();

  // ---- phase 2: QKV. Q^T,K^T transposed-GEMM; V normal-GEMM. wave = head ----
  {
    f32x4 aqk[4][4];   // [chtile 0..3 = Q0,Q1,K0,K1][token tile]
    f32x4 av[4][2];    // [token tile][d tile]
    #pragma unroll
    for (int ct = 0; ct < 4; ++ct){
      const f32x4 bq = *(const f32x4*)(qkv_b + wid*96 + ct*16 + kg*4);
      #pragma unroll
      for (int tt = 0; tt < 4; ++tt) aqk[ct][tt] = bq;
    }
    #pragma unroll
    for (int nt = 0; nt < 2; ++nt){
      const float bv = qkv_b[wid*96 + 64 + nt*16 + r15];
      const f32x4 bv4 = {bv, bv, bv, bv};
      #pragma unroll
      for (int mt = 0; mt < 4; ++mt) av[mt][nt] = bv4;
    }
    #pragma unroll
    for (int kk = 0; kk < 4; ++kk){
      bf16x8 L[4], aW[4], bWv[2];
      const int c0 = kk*32 + kg*8;
      #pragma unroll
      for (int t = 0; t < 4; ++t){
        const int row = t*16 + r15;
        L[t] = *(const bf16x8*)&sLN[row*128 + (c0 ^ ((row & 7) << 3))];
      }
      #pragma unroll
      for (int ct = 0; ct < 4; ++ct)
        aW[ct] = *(const bf16x8*)(rep_qkv + (size_t)((kk*24 + wid*6 + ct)*64 + lane)*8);
      #pragma unroll
      for (int nt = 0; nt < 2; ++nt)
        bWv[nt] = *(const bf16x8*)(rep_qkv + (size_t)((kk*24 + wid*6 + 4 + nt)*64 + lane)*8);
      #pragma unroll
      for (int ct = 0; ct < 4; ++ct)
        #pragma unroll
        for (int tt = 0; tt < 4; ++tt)
          aqk[ct][tt] = __builtin_amdgcn_mfma_f32_16x16x32_bf16(aW[ct], L[tt], aqk[ct][tt], 0, 0, 0);
      #pragma unroll
      for (int mt = 0; mt < 4; ++mt)
        #pragma unroll
        for (int nt = 0; nt < 2; ++nt)
          av[mt][nt] = __builtin_amdgcn_mfma_f32_16x16x32_bf16(L[mt], bWv[nt], av[mt][nt], 0, 0, 0);
    }
    // packed stores: Q (scaled), K into [tok][d_all]; V into V^T [d_all][tok]
    #pragma unroll
    for (int ct = 0; ct < 4; ++ct){
      u16* dst = (ct < 2) ? sQ : sK;
      const float scl = (ct < 2) ? 0.17677669529663687f : 1.0f;
      const int colu = wid*32 + (ct & 1)*16 + kg*4;
      #pragma unroll
      for (int tt = 0; tt < 4; ++tt){
        const int row = tt*16 + r15;
        bf16x4 pk;
        #pragma unroll
        for (int rg = 0; rg < 4; ++rg) pk[rg] = (short)f2bf(aqk[ct][tt][rg] * scl);
        *(bf16x4*)&dst[row*128 + (colu ^ ((row & 7) << 3))] = pk;
      }
    }
    #pragma unroll
    for (int nt = 0; nt < 2; ++nt){
      const int row = wid*32 + nt*16 + r15;       // d_all
      #pragma unroll
      for (int mt = 0; mt < 4; ++mt){
        const int colu = mt*16 + kg*4;            // token
        bf16x4 pk;
        #pragma unroll
        for (int rg = 0; rg < 4; ++rg) pk[rg] = (short)f2bf(av[mt][nt][rg]);
        *(bf16x4*)&sV[row*64 + (colu ^ ((row & 7) << 3))] = pk;
      }
    }
  }
  // own-wave tiles only -> no barrier before S^T

  // ---- phase 3: S^T = K·Q^T + bias^T (C-input), softmax over k ----
  f32x4 s4[4][4];   // [k tile][q tile]
  {
    bf16x8 aK[4], bQ[4];
    #pragma unroll
    for (int t = 0; t < 4; ++t){
      const int row = t*16 + r15;
      const int off = (wid*32 + kg*8) ^ ((row & 7) << 3);
      aK[t] = *(const bf16x8*)&sK[row*128 + off];
      bQ[t] = *(const bf16x8*)&sQ[row*128 + off];
    }
    #pragma unroll
    for (int mtk = 0; mtk < 4; ++mtk)
      #pragma unroll
      for (int ntq = 0; ntq < 4; ++ntq){
        const f32x4 cb4 = *(const f32x4*)(bias_exp + (size_t)(((wid*4 + mtk)*4 + ntq)*64 + lane)*4);
        s4[mtk][ntq] = __builtin_amdgcn_mfma_f32_16x16x32_bf16(aK[mtk], bQ[ntq], cb4, 0, 0, 0);
      }
  }
  #pragma unroll
  for (int ntq = 0; ntq < 4; ++ntq){
    float mx = s4[0][ntq][0];
    #pragma unroll
    for (int mtk = 0; mtk < 4; ++mtk)
      #pragma unroll
      for (int rg = 0; rg < 4; ++rg) mx = fmaxf(mx, s4[mtk][ntq][rg]);
    mx = fmaxf(mx, __shfl_xor(mx, 16));
    mx = fmaxf(mx, __shfl_xor(mx, 32));
    float sum = 0.f;
    #pragma unroll
    for (int mtk = 0; mtk < 4; ++mtk)
      #pragma unroll
      for (int rg = 0; rg < 4; ++rg){
        const float e = __expf(s4[mtk][ntq][rg] - mx);
        s4[mtk][ntq][rg] = e; sum += e;
      }
    sum += __shfl_xor(sum, 16);
    sum += __shfl_xor(sum, 32);
    const float inv = __builtin_amdgcn_rcpf(sum);
    #pragma unroll
    for (int mtk = 0; mtk < 4; ++mtk)
      #pragma unroll
      for (int rg = 0; rg < 4; ++rg) s4[mtk][ntq][rg] *= inv;
  }
  __syncthreads();   // all waves' Q/K reads done; P may overlay Q/K
  #pragma unroll
  for (int ntq = 0; ntq < 4; ++ntq){
    const int row = ntq*16 + r15;                 // q
    #pragma unroll
    for (int mtk = 0; mtk < 4; ++mtk){
      const int colu = wid*64 + mtk*16 + kg*4;    // k_all
      bf16x4 pk;
      #pragma unroll
      for (int rg = 0; rg < 4; ++rg) pk[rg] = (short)f2bf(s4[mtk][ntq][rg]);
      *(bf16x4*)&sP[row*256 + (colu ^ ((row & 7) << 3))] = pk;
    }
  }

  // ---- phase 4: O = P @ V (own-wave tiles; no barrier) ----
  f32x4 o4[4][2];
  #pragma unroll
  for (int mt = 0; mt < 4; ++mt){ o4[mt][0] = z4; o4[mt][1] = z4; }
  #pragma unroll
  for (int ks = 0; ks < 2; ++ks){
    bf16x8 aP[4], bV[2];
    #pragma unroll
    for (int mt = 0; mt < 4; ++mt){
      const int row = mt*16 + r15;
      const int colu = wid*64 + ks*32 + kg*8;
      aP[mt] = *(const bf16x8*)&sP[row*256 + (colu ^ ((row & 7) << 3))];
    }
    #pragma unroll
    for (int nt = 0; nt < 2; ++nt){
      const int row = wid*32 + nt*16 + r15;       // d_all
      const int colu = ks*32 + kg*8;              // token
      bV[nt] = *(const bf16x8*)&sV[row*64 + (colu ^ ((row & 7) << 3))];
    }
    #pragma unroll
    for (int mt = 0; mt < 4; ++mt)
      #pragma unroll
      for (int nt = 0; nt < 2; ++nt)
        o4[mt][nt] = __builtin_amdgcn_mfma_f32_16x16x32_bf16(aP[mt], bV[nt], o4[mt][nt], 0, 0, 0);
  }
  #pragma unroll
  for (int mt = 0; mt < 4; ++mt)
    #pragma unroll
    for (int nt = 0; nt < 2; ++nt)
      #pragma unroll
      for (int rg = 0; rg < 4; ++rg){
        const int row = mt*16 + kg*4 + rg, col = wid*32 + nt*16 + r15;
        sO[row*128 + (col ^ ((row & 7) << 3))] = f2bf(o4[mt][nt][rg]);
      }
  __syncthreads();   // all O written (and all P/V reads done)

  // ---- phase 5: proj (wave owns 32 out cols), stage f32 ----
  {
    f32x4 po[4][2];
    #pragma unroll
    for (int nt = 0; nt < 2; ++nt){
      const float pb = proj_b[wid*32 + nt*16 + r15];
      const f32x4 pb4 = {pb, pb, pb, pb};
      #pragma unroll
      for (int mt = 0; mt < 4; ++mt) po[mt][nt] = pb4;
    }
    #pragma unroll
    for (int kk = 0; kk < 4; ++kk){
      bf16x8 aO[4], bP[2];
      const int c0 = kk*32 + kg*8;
      #pragma unroll
      for (int mt = 0; mt < 4; ++mt){
        const int row = mt*16 + r15;
        aO[mt] = *(const bf16x8*)&sO[row*128 + (c0 ^ ((row & 7) << 3))];
      }
      #pragma unroll
      for (int nt = 0; nt < 2; ++nt)
        bP[nt] = *(const bf16x8*)(rep_proj + (size_t)((kk*8 + wid*2 + nt)*64 + lane)*8);
      #pragma unroll
      for (int mt = 0; mt < 4; ++mt)
        #pragma unroll
        for (int nt = 0; nt < 2; ++nt)
          po[mt][nt] = __builtin_amdgcn_mfma_f32_16x16x32_bf16(aO[mt], bP[nt], po[mt][nt], 0, 0, 0);
    }
    #pragma unroll
    for (int nt = 0; nt < 2; ++nt){
      const int col = wid*32 + nt*16 + r15;
      #pragma unroll
      for (int mt = 0; mt < 4; ++mt)
        #pragma unroll
        for (int rg = 0; rg < 4; ++rg){
          const int row = mt*16 + kg*4 + rg;
          stg[row*128 + (col ^ ((row & 7) << 2))] = po[mt][nt][rg];
        }
    }
  }
  __syncthreads();

  // ---- phase 6: residual (x reloaded) + scatter to image layout ----
  #pragma unroll
  for (int it = 0; it < 4; ++it){
    const int r = it * 16 + rb;
    const int pix = ((r >> 3) * 8 + ihb) * 64 + (r & 7) * 8 + iwb;
    const int m = (r & 7) << 2;
    f32x4 x0 = *(const f32x4*)(xb + (size_t)pix * 128 + c0g);
    f32x4 x1 = *(const f32x4*)(xb + (size_t)pix * 128 + c0g + 4);
    f32x4 p0 = *(const f32x4*)&stg[r*128 + (c0g ^ m)];
    f32x4 p1 = *(const f32x4*)&stg[r*128 + ((c0g + 4) ^ m)];
    f32x4 o0, o1;
    #pragma unroll
    for (int j = 0; j < 4; ++j){ o0[j] = x0[j] + p0[j]; o1[j] = x1[j] + p1[j]; }
    *(f32x4*)(mb + (size_t)pix * 128 + c0g)     = o0;
    *(f32x4*)(mb + (size_t)pix * 128 + c0g + 4) = o1;
  }
}

// ---------------------------------------------------------------------------
// K2: LN2 + MLP in transposed orientation (Ht = W1^T·LN^T; out^T = W2^T·Ht^T).
// GELU intermediate written as packed b64; epilogue writes msa+mlp directly.
// LDS 48 KB -> 3 blocks/CU. msa aliases out (same-thread read-then-write).
// ---------------------------------------------------------------------------
__global__ __launch_bounds__(256, 3)
void mlp_kernel(const float* msa,
                const float* __restrict__ ln2_g, const float* __restrict__ ln2_b,
                const u16* __restrict__ rep_w1, const u16* __restrict__ rep_w2,
                const float* __restrict__ mlp_b1, const float* __restrict__ mlp_b2,
                float* out){
  __shared__ __align__(16) u16 sMem[24576];  // sH [0,8K) | sG0 [8K,16K) | sG1 [16K,24K)
  u16* sH = sMem;
  const int tid = threadIdx.x, lane = tid & 63, wid = tid >> 6;
  const size_t r0 = (size_t)blockIdx.x * 64;
  const int rb = tid >> 4, cb = tid & 15, c0g = cb * 8;
  const int r15 = lane & 15, kg = lane >> 4;

  // ---- LN2 -> sH (bf16, swizzled) ----
  {
    float g8[8], b8[8];
    *(f32x4*)&g8[0] = *(const f32x4*)(ln2_g + c0g);
    *(f32x4*)&g8[4] = *(const f32x4*)(ln2_g + c0g + 4);
    *(f32x4*)&b8[0] = *(const f32x4*)(ln2_b + c0g);
    *(f32x4*)&b8[4] = *(const f32x4*)(ln2_b + c0g + 4);
    #pragma unroll
    for (int it = 0; it < 4; ++it){
      const int r = it * 16 + rb;
      float fl[8];
      *(f32x4*)&fl[0] = *(const f32x4*)(msa + (r0 + r) * 128 + c0g);
      *(f32x4*)&fl[4] = *(const f32x4*)(msa + (r0 + r) * 128 + c0g + 4);
      float s = 0.f, sq = 0.f;
      #pragma unroll
      for (int j = 0; j < 8; ++j){ s += fl[j]; sq += fl[j]*fl[j]; }
      #pragma unroll
      for (int m = 1; m < 16; m <<= 1){ s += __shfl_xor(s, m); sq += __shfl_xor(sq, m); }
      const float mean = s * (1.f/128.f);
      const float rs = rsqrtf(sq * (1.f/128.f) - mean*mean + 1e-5f);
      bf16x8 o;
      #pragma unroll
      for (int j = 0; j < 8; ++j)
        o[j] = (short)f2bf((fl[j]-mean)*rs*g8[j] + b8[j]);
      *(bf16x8*)&sH[r*128 + (c0g ^ ((r & 7) << 3))] = o;
    }
  }
  __syncthreads();

  f32x4 accO[2][4];   // [out tile][token tile], init with b2
  #pragma unroll
  for (int ot = 0; ot < 2; ++ot){
    const f32x4 b2v = *(const f32x4*)(mlp_b2 + (wid*2 + ot)*16 + kg*4);
    #pragma unroll
    for (int tt = 0; tt < 4; ++tt) accO[ot][tt] = b2v;
  }

  #pragma unroll
  for (int c = 0; c < 4; ++c){      // 4 chunks of 128 hidden
    u16* sG = sMem + 8192 + (c & 1)*8192;
    f32x4 t4[2][4];                 // [hidden tile][token tile], init with b1
    #pragma unroll
    for (int ht = 0; ht < 2; ++ht){
      const f32x4 b1v = *(const f32x4*)(mlp_b1 + c*128 + (wid*2 + ht)*16 + kg*4);
      #pragma unroll
      for (int tt = 0; tt < 4; ++tt) t4[ht][tt] = b1v;
    }
    #pragma unroll
    for (int kk = 0; kk < 4; ++kk){
      bf16x8 aW[2], bL[4];
      const int c0 = kk*32 + kg*8;
      #pragma unroll
      for (int ht = 0; ht < 2; ++ht)
        aW[ht] = *(const bf16x8*)(rep_w1 + (size_t)((kk*32 + c*8 + wid*2 + ht)*64 + lane)*8);
      #pragma unroll
      for (int tt = 0; tt < 4; ++tt){
        const int row = tt*16 + r15;
        bL[tt] = *(const bf16x8*)&sH[row*128 + (c0 ^ ((row & 7) << 3))];
      }
      #pragma unroll
      for (int ht = 0; ht < 2; ++ht)
        #pragma unroll
        for (int tt = 0; tt < 4; ++tt)
          t4[ht][tt] = __builtin_amdgcn_mfma_f32_16x16x32_bf16(aW[ht], bL[tt], t4[ht][tt], 0, 0, 0);
    }
    // sigmoid-GELU + packed b64 store into sG [token][hidden_local]
    #pragma unroll
    for (int ht = 0; ht < 2; ++ht){
      const int colu = (wid*2 + ht)*16 + kg*4;
      #pragma unroll
      for (int tt = 0; tt < 4; ++tt){
        const int row = tt*16 + r15;
        bf16x4 pk;
        #pragma unroll
        for (int rg = 0; rg < 4; ++rg){
          const float v = t4[ht][tt][rg];
          const float e = __expf(-1.702f * v);
          const float g = v * __builtin_amdgcn_rcpf(1.f + e);
          pk[rg] = (short)f2bf(g);
        }
        *(bf16x4*)&sG[row*128 + (colu ^ ((row & 7) << 3))] = pk;
      }
    }
    __syncthreads();
    #pragma unroll
    for (int kk = 0; kk < 4; ++kk){
      bf16x8 aW2[2], bG[4];
      const int c0 = kk*32 + kg*8;
      #pragma unroll
      for (int ot = 0; ot < 2; ++ot)
        aW2[ot] = *(const bf16x8*)(rep_w2 + (size_t)(((c*4 + kk)*8 + wid*2 + ot)*64 + lane)*8);
      #pragma unroll
      for (int tt = 0; tt < 4; ++tt){
        const int row = tt*16 + r15;
        bG[tt] = *(const bf16x8*)&sG[row*128 + (c0 ^ ((row & 7) << 3))];
      }
      #pragma unroll
      for (int ot = 0; ot < 2; ++ot)
        #pragma unroll
        for (int tt = 0; tt < 4; ++tt)
          accO[ot][tt] = __builtin_amdgcn_mfma_f32_16x16x32_bf16(aW2[ot], bG[tt], accO[ot][tt], 0, 0, 0);
    }
    // no trailing sync: next chunk writes the other sG buffer
  }

  // ---- epilogue: residual + direct f32x4 global store ----
  #pragma unroll
  for (int ot = 0; ot < 2; ++ot){
    const int chb = (wid*2 + ot)*16 + kg*4;
    #pragma unroll
    for (int tt = 0; tt < 4; ++tt){
      const size_t tok = r0 + tt*16 + r15;
      const f32x4 m = *(const f32x4*)(msa + tok*128 + chb);
      f32x4 o;
      #pragma unroll
      for (int rg = 0; rg < 4; ++rg) o[rg] = m[rg] + accO[ot][tt][rg];
      *(f32x4*)(out + tok*128 + chb) = o;
    }
  }
}

// ---------------------------------------------------------------------------
// ws layout (bytes): rq 0..98304 | rp ..131072 | r1 ..262144 | r2 ..393216 |
// be ..458752.  msa staging lives in d_out (fully rewritten every call).
// ---------------------------------------------------------------------------
extern "C" void kernel_launch(void* const* d_in, const int* in_sizes, int n_in,
                              void* d_out, int out_size, void* d_ws, size_t ws_size,
                              hipStream_t stream){
  (void)in_sizes; (void)n_in; (void)out_size; (void)ws_size;
  const float* x      = (const float*)d_in[0];
  const float* qkv_w  = (const float*)d_in[1];
  const float* qkv_b  = (const float*)d_in[2];
  const float* proj_w = (const float*)d_in[3];
  const float* proj_b = (const float*)d_in[4];
  const float* tbl    = (const float*)d_in[5];
  const float* ln1_g  = (const float*)d_in[6];
  const float* ln1_b  = (const float*)d_in[7];
  const float* ln2_g  = (const float*)d_in[8];
  const float* ln2_b  = (const float*)d_in[9];
  const float* w1     = (const float*)d_in[10];
  const float* b1     = (const float*)d_in[11];
  const float* w2     = (const float*)d_in[12];
  const float* b2     = (const float*)d_in[13];

  char* ws = (char*)d_ws;
  u16*   rq  = (u16*)ws;
  u16*   rp  = (u16*)(ws + 98304);
  u16*   r1  = (u16*)(ws + 131072);
  u16*   r2  = (u16*)(ws + 262144);
  float* be  = (float*)(ws + 393216);
  float* msa = (float*)d_out;

  hipLaunchKernelGGL(repack_kernel, dim3(256), dim3(256), 0, stream,
                     qkv_w, proj_w, w1, w2, tbl, rq, rp, r1, r2, be);
  hipLaunchKernelGGL(attn_kernel, dim3(2048), dim3(256), 0, stream,
                     x, qkv_b, proj_b, ln1_g, ln1_b, rq, rp, be, msa);
  hipLaunchKernelGGL(mlp_kernel, dim3(2048), dim3(256), 0, stream,
                     msa, ln2_g, ln2_b, r1, r2, b1, b2, (float*)d_out);
}

// Round 5
// 122.166 us; speedup vs baseline: 1.5058x; 1.0738x over previous
//
#include <hip/hip_runtime.h>

typedef __attribute__((ext_vector_type(4))) float f32x4;
typedef __attribute__((ext_vector_type(8))) short bf16x8;
typedef __attribute__((ext_vector_type(4))) short bf16x4;
typedef unsigned short u16;

__device__ __forceinline__ u16 f2bf(float f){
  unsigned u = __float_as_uint(f);
  u += 0x7FFFu + ((u >> 16) & 1u);
  return (u16)(u >> 16);
}

// ---------------------------------------------------------------------------
// K0: repack f32 weights into bf16 MFMA fragment order + expand relative
// bias into MFMA C-fragment layout for S^T = K·Q^T (row=k_token, col=q_token).
// Fragment (kk, nt, lane, j) holds W[k = kk*32 + (lane>>4)*8 + j][nt*16 + (lane&15)].
// ---------------------------------------------------------------------------
__global__ void repack_kernel(const float* __restrict__ qkv_w, const float* __restrict__ proj_w,
                              const float* __restrict__ w1, const float* __restrict__ w2,
                              const float* __restrict__ tbl,
                              u16* __restrict__ rq, u16* __restrict__ rp,
                              u16* __restrict__ r1, u16* __restrict__ r2,
                              float* __restrict__ be){
  const int i = blockIdx.x * 256 + threadIdx.x;          // 0 .. 65535
  const int j = i & 7, lane = (i >> 3) & 63, f = i >> 9;
  const int kr = (lane >> 4) * 8 + j;                    // k within 32-chunk
  const int c16 = lane & 15;
  if (i < 49152){ int nt = f % 24, kk = f / 24; rq[i] = f2bf(qkv_w[(kk*32 + kr)*384 + nt*16 + c16]); }
  if (i < 16384){ int nt = f & 7,  kk = f >> 3; rp[i] = f2bf(proj_w[(kk*32 + kr)*128 + nt*16 + c16]); }
  if (i < 65536){ int nt = f & 31, kk = f >> 5; r1[i] = f2bf(w1[(kk*32 + kr)*512 + nt*16 + c16]); }
  if (i < 65536){ int nt = f & 7,  kk = f >> 3; r2[i] = f2bf(w2[(kk*32 + kr)*128 + nt*16 + c16]); }
  if (i < 16384){
    int rg = i & 3, ln = (i >> 2) & 63, g = i >> 8;
    int nt = g & 3, mt = (g >> 2) & 3, h = g >> 4;
    int row = mt*16 + (ln >> 4)*4 + rg;   // k_token (C row)
    int col = nt*16 + (ln & 15);          // q_token (C col)
    int rel = ((col >> 3) - (row >> 3) + 7) * 15 + ((col & 7) - (row & 7) + 7);
    be[i] = tbl[rel*4 + h];
  }
}

// ---------------------------------------------------------------------------
// K1: fully fused Swin block, one workgroup per 64-token window.
// 256 threads (4 waves, wave == head for attn). LDS 64 KB -> 2 blocks/CU.
// msa lives only in LDS (f32); d_out written exactly once.
// Every phase boundary is barrier-separated (no own-wave-no-barrier tricks).
// LDS byte map:
//   [0,16K)   sLN -> sO -> sH
//   [16K,48K) sQ[16K,32K)+sK[32K,48K) -> sP -> stg(f32 msa)
//   [48K,64K) sV -> sG
// ---------------------------------------------------------------------------
__global__ __launch_bounds__(256, 2)
void block_kernel(const float* __restrict__ x,
                  const float* __restrict__ qkv_b, const float* __restrict__ proj_b,
                  const float* __restrict__ ln1_g, const float* __restrict__ ln1_b,
                  const float* __restrict__ ln2_g, const float* __restrict__ ln2_b,
                  const u16* __restrict__ rep_qkv, const u16* __restrict__ rep_proj,
                  const u16* __restrict__ rep_w1, const u16* __restrict__ rep_w2,
                  const float* __restrict__ mlp_b1, const float* __restrict__ mlp_b2,
                  const float* __restrict__ bias_exp,
                  float* __restrict__ out){
  __shared__ __align__(16) u16 smem[32768];
  u16* sLN = smem;                    // [64][128] bf16
  u16* sQ  = smem + 8192;             // [64 tok][128 d_all]
  u16* sK  = smem + 16384;            // [64 tok][128 d_all]
  u16* sV  = smem + 24576;            // V^T [128 d_all][64 tok]
  u16* sP  = smem + 8192;             // [64 q][256 k_all]
  u16* sO  = smem;                    // [64 tok][128 ch]
  u16* sH  = smem;                    // [64 tok][128 ch] LN2 bf16
  u16* sG  = smem + 24576;            // [64 tok][128 hid] gelu bf16
  float* stg = (float*)(smem + 8192); // [64][128] f32 (proj -> msa)

  const int tid = threadIdx.x, lane = tid & 63, wid = tid >> 6;
  const int wdw = blockIdx.x;
  const int bb = wdw >> 6, ihb = (wdw >> 3) & 7, iwb = wdw & 7;
  const float* xb = x + (size_t)bb * 4096 * 128;
  float* ob = out + (size_t)bb * 4096 * 128;
  const f32x4 z4 = {0.f, 0.f, 0.f, 0.f};
  const int rb = tid >> 4, cb = tid & 15, c0g = cb * 8;
  const int r15 = lane & 15, kg = lane >> 4;
  float xs[4][8];                     // window residual kept in registers

  // ---- P1: load window + LN1 -> sLN ----
  {
    float g8[8], b8[8];
    *(f32x4*)&g8[0] = *(const f32x4*)(ln1_g + c0g);
    *(f32x4*)&g8[4] = *(const f32x4*)(ln1_g + c0g + 4);
    *(f32x4*)&b8[0] = *(const f32x4*)(ln1_b + c0g);
    *(f32x4*)&b8[4] = *(const f32x4*)(ln1_b + c0g + 4);
    #pragma unroll
    for (int it = 0; it < 4; ++it){
      const int r = it * 16 + rb;
      const int pix = ((r >> 3) * 8 + ihb) * 64 + (r & 7) * 8 + iwb;
      *(f32x4*)&xs[it][0] = *(const f32x4*)(xb + (size_t)pix * 128 + c0g);
      *(f32x4*)&xs[it][4] = *(const f32x4*)(xb + (size_t)pix * 128 + c0g + 4);
      float s = 0.f, sq = 0.f;
      #pragma unroll
      for (int j = 0; j < 8; ++j){ s += xs[it][j]; sq += xs[it][j]*xs[it][j]; }
      #pragma unroll
      for (int m = 1; m < 16; m <<= 1){ s += __shfl_xor(s, m); sq += __shfl_xor(sq, m); }
      const float mean = s * (1.f/128.f);
      const float rs = rsqrtf(sq * (1.f/128.f) - mean*mean + 1e-5f);
      bf16x8 o;
      #pragma unroll
      for (int j = 0; j < 8; ++j)
        o[j] = (short)f2bf((xs[it][j]-mean)*rs*g8[j] + b8[j]);
      *(bf16x8*)&sLN[r*128 + (c0g ^ ((r & 7) << 3))] = o;
    }
  }
  __syncthreads();

  // ---- P2: QKV. Q^T,K^T transposed-GEMM; V normal-GEMM. wave = head ----
  {
    f32x4 aqk[4][4];   // [chtile Q0,Q1,K0,K1][token tile]
    f32x4 av[4][2];    // [token tile][d tile]
    #pragma unroll
    for (int ct = 0; ct < 4; ++ct){
      const f32x4 bq = *(const f32x4*)(qkv_b + wid*96 + ct*16 + kg*4);
      #pragma unroll
      for (int tt = 0; tt < 4; ++tt) aqk[ct][tt] = bq;
    }
    #pragma unroll
    for (int nt = 0; nt < 2; ++nt){
      const float bv = qkv_b[wid*96 + 64 + nt*16 + r15];
      const f32x4 bv4 = {bv, bv, bv, bv};
      #pragma unroll
      for (int mt = 0; mt < 4; ++mt) av[mt][nt] = bv4;
    }
    #pragma unroll
    for (int kk = 0; kk < 4; ++kk){
      bf16x8 L[4], aW[4], bWv[2];
      const int c0 = kk*32 + kg*8;
      #pragma unroll
      for (int t = 0; t < 4; ++t){
        const int row = t*16 + r15;
        L[t] = *(const bf16x8*)&sLN[row*128 + (c0 ^ ((row & 7) << 3))];
      }
      #pragma unroll
      for (int ct = 0; ct < 4; ++ct)
        aW[ct] = *(const bf16x8*)(rep_qkv + (size_t)((kk*24 + wid*6 + ct)*64 + lane)*8);
      #pragma unroll
      for (int nt = 0; nt < 2; ++nt)
        bWv[nt] = *(const bf16x8*)(rep_qkv + (size_t)((kk*24 + wid*6 + 4 + nt)*64 + lane)*8);
      #pragma unroll
      for (int ct = 0; ct < 4; ++ct)
        #pragma unroll
        for (int tt = 0; tt < 4; ++tt)
          aqk[ct][tt] = __builtin_amdgcn_mfma_f32_16x16x32_bf16(aW[ct], L[tt], aqk[ct][tt], 0, 0, 0);
      #pragma unroll
      for (int mt = 0; mt < 4; ++mt)
        #pragma unroll
        for (int nt = 0; nt < 2; ++nt)
          av[mt][nt] = __builtin_amdgcn_mfma_f32_16x16x32_bf16(L[mt], bWv[nt], av[mt][nt], 0, 0, 0);
    }
    // packed stores: Q (pre-scaled), K into [tok][d]; V into V^T [d][tok]
    #pragma unroll
    for (int ct = 0; ct < 4; ++ct){
      u16* dst = (ct < 2) ? sQ : sK;
      const float scl = (ct < 2) ? 0.17677669529663687f : 1.0f;
      const int colu = wid*32 + (ct & 1)*16 + kg*4;
      #pragma unroll
      for (int tt = 0; tt < 4; ++tt){
        const int row = tt*16 + r15;
        bf16x4 pk;
        #pragma unroll
        for (int rg = 0; rg < 4; ++rg) pk[rg] = (short)f2bf(aqk[ct][tt][rg] * scl);
        *(bf16x4*)&dst[row*128 + (colu ^ ((row & 7) << 3))] = pk;
      }
    }
    #pragma unroll
    for (int nt = 0; nt < 2; ++nt){
      const int row = wid*32 + nt*16 + r15;       // d_all
      #pragma unroll
      for (int mt = 0; mt < 4; ++mt){
        const int colu = mt*16 + kg*4;            // token
        bf16x4 pk;
        #pragma unroll
        for (int rg = 0; rg < 4; ++rg) pk[rg] = (short)f2bf(av[mt][nt][rg]);
        *(bf16x4*)&sV[row*64 + (colu ^ ((row & 7) << 3))] = pk;
      }
    }
  }
  __syncthreads();

  // ---- P3: S^T = K·Q^T + bias (C-input), softmax over k ----
  f32x4 s4[4][4];   // [k tile][q tile]
  {
    bf16x8 aK[4], bQ[4];
    #pragma unroll
    for (int t = 0; t < 4; ++t){
      const int row = t*16 + r15;
      const int off = (wid*32 + kg*8) ^ ((row & 7) << 3);
      aK[t] = *(const bf16x8*)&sK[row*128 + off];
      bQ[t] = *(const bf16x8*)&sQ[row*128 + off];
    }
    #pragma unroll
    for (int mtk = 0; mtk < 4; ++mtk)
      #pragma unroll
      for (int ntq = 0; ntq < 4; ++ntq){
        const f32x4 cb4 = *(const f32x4*)(bias_exp + (size_t)(((wid*4 + mtk)*4 + ntq)*64 + lane)*4);
        s4[mtk][ntq] = __builtin_amdgcn_mfma_f32_16x16x32_bf16(aK[mtk], bQ[ntq], cb4, 0, 0, 0);
      }
  }
  #pragma unroll
  for (int ntq = 0; ntq < 4; ++ntq){
    float mx = s4[0][ntq][0];
    #pragma unroll
    for (int mtk = 0; mtk < 4; ++mtk)
      #pragma unroll
      for (int rg = 0; rg < 4; ++rg) mx = fmaxf(mx, s4[mtk][ntq][rg]);
    mx = fmaxf(mx, __shfl_xor(mx, 16));
    mx = fmaxf(mx, __shfl_xor(mx, 32));
    float sum = 0.f;
    #pragma unroll
    for (int mtk = 0; mtk < 4; ++mtk)
      #pragma unroll
      for (int rg = 0; rg < 4; ++rg){
        const float e = __expf(s4[mtk][ntq][rg] - mx);
        s4[mtk][ntq][rg] = e; sum += e;
      }
    sum += __shfl_xor(sum, 16);
    sum += __shfl_xor(sum, 32);
    const float inv = __builtin_amdgcn_rcpf(sum);
    #pragma unroll
    for (int mtk = 0; mtk < 4; ++mtk)
      #pragma unroll
      for (int rg = 0; rg < 4; ++rg) s4[mtk][ntq][rg] *= inv;
  }
  __syncthreads();   // all Q/K reads done; P overlays Q/K
  #pragma unroll
  for (int ntq = 0; ntq < 4; ++ntq){
    const int row = ntq*16 + r15;                 // q
    #pragma unroll
    for (int mtk = 0; mtk < 4; ++mtk){
      const int colu = wid*64 + mtk*16 + kg*4;    // k_all
      bf16x4 pk;
      #pragma unroll
      for (int rg = 0; rg < 4; ++rg) pk[rg] = (short)f2bf(s4[mtk][ntq][rg]);
      *(bf16x4*)&sP[row*256 + (colu ^ ((row & 7) << 3))] = pk;
    }
  }
  __syncthreads();   // P fully written

  // ---- P4: O^T = V^T·P^T -> sO[tok][ch] (packed b64 stores) ----
  {
    f32x4 o4[2][4];   // [d tile][q tile]
    #pragma unroll
    for (int dt = 0; dt < 2; ++dt)
      #pragma unroll
      for (int qt = 0; qt < 4; ++qt) o4[dt][qt] = z4;
    #pragma unroll
    for (int ks = 0; ks < 2; ++ks){
      bf16x8 aV[2], bP[4];
      #pragma unroll
      for (int dt = 0; dt < 2; ++dt){
        const int rowd = wid*32 + dt*16 + r15;
        aV[dt] = *(const bf16x8*)&sV[rowd*64 + ((ks*32 + kg*8) ^ ((rowd & 7) << 3))];
      }
      #pragma unroll
      for (int qt = 0; qt < 4; ++qt){
        const int rowq = qt*16 + r15;
        bP[qt] = *(const bf16x8*)&sP[rowq*256 + ((wid*64 + ks*32 + kg*8) ^ ((rowq & 7) << 3))];
      }
      #pragma unroll
      for (int dt = 0; dt < 2; ++dt)
        #pragma unroll
        for (int qt = 0; qt < 4; ++qt)
          o4[dt][qt] = __builtin_amdgcn_mfma_f32_16x16x32_bf16(aV[dt], bP[qt], o4[dt][qt], 0, 0, 0);
    }
    #pragma unroll
    for (int dt = 0; dt < 2; ++dt){
      const int dbase = wid*32 + dt*16 + kg*4;
      #pragma unroll
      for (int qt = 0; qt < 4; ++qt){
        const int q = qt*16 + r15;
        bf16x4 pk;
        #pragma unroll
        for (int rg = 0; rg < 4; ++rg) pk[rg] = (short)f2bf(o4[dt][qt][rg]);
        *(bf16x4*)&sO[q*128 + (dbase ^ ((q & 7) << 3))] = pk;
      }
    }
  }
  __syncthreads();   // O complete; P/V reads done

  // ---- P5: proj^T = Wp^T·O^T -> stg (f32x4 stores, [tok][ch]) ----
  {
    f32x4 po[2][4];   // [out-ch tile][token tile]
    #pragma unroll
    for (int ot = 0; ot < 2; ++ot){
      const f32x4 pb4 = *(const f32x4*)(proj_b + (wid*2 + ot)*16 + kg*4);
      #pragma unroll
      for (int tt = 0; tt < 4; ++tt) po[ot][tt] = pb4;
    }
    #pragma unroll
    for (int kk = 0; kk < 4; ++kk){
      bf16x8 aWp[2], bO[4];
      #pragma unroll
      for (int ot = 0; ot < 2; ++ot)
        aWp[ot] = *(const bf16x8*)(rep_proj + (size_t)((kk*8 + wid*2 + ot)*64 + lane)*8);
      #pragma unroll
      for (int tt = 0; tt < 4; ++tt){
        const int row = tt*16 + r15;
        bO[tt] = *(const bf16x8*)&sO[row*128 + ((kk*32 + kg*8) ^ ((row & 7) << 3))];
      }
      #pragma unroll
      for (int ot = 0; ot < 2; ++ot)
        #pragma unroll
        for (int tt = 0; tt < 4; ++tt)
          po[ot][tt] = __builtin_amdgcn_mfma_f32_16x16x32_bf16(aWp[ot], bO[tt], po[ot][tt], 0, 0, 0);
    }
    #pragma unroll
    for (int ot = 0; ot < 2; ++ot){
      const int cbase = (wid*2 + ot)*16 + kg*4;
      #pragma unroll
      for (int tt = 0; tt < 4; ++tt){
        const int tok = tt*16 + r15;
        *(f32x4*)&stg[tok*128 + (cbase ^ ((tok & 7) << 2))] = po[ot][tt];
      }
    }
  }
  __syncthreads();

  // ---- P6: msa = x + proj (stg in place, f32); LN2 -> sH ----
  {
    float g8[8], b8[8];
    *(f32x4*)&g8[0] = *(const f32x4*)(ln2_g + c0g);
    *(f32x4*)&g8[4] = *(const f32x4*)(ln2_g + c0g + 4);
    *(f32x4*)&b8[0] = *(const f32x4*)(ln2_b + c0g);
    *(f32x4*)&b8[4] = *(const f32x4*)(ln2_b + c0g + 4);
    #pragma unroll
    for (int it = 0; it < 4; ++it){
      const int r = it * 16 + rb;
      const int m4 = (r & 7) << 2;
      f32x4 p0 = *(const f32x4*)&stg[r*128 + (c0g ^ m4)];
      f32x4 p1 = *(const f32x4*)&stg[r*128 + ((c0g + 4) ^ m4)];
      float ms[8];
      #pragma unroll
      for (int j = 0; j < 4; ++j){ ms[j] = xs[it][j] + p0[j]; ms[4+j] = xs[it][4+j] + p1[j]; }
      #pragma unroll
      for (int j = 0; j < 4; ++j){ p0[j] = ms[j]; p1[j] = ms[4+j]; }
      *(f32x4*)&stg[r*128 + (c0g ^ m4)] = p0;
      *(f32x4*)&stg[r*128 + ((c0g + 4) ^ m4)] = p1;
      float s = 0.f, sq = 0.f;
      #pragma unroll
      for (int j = 0; j < 8; ++j){ s += ms[j]; sq += ms[j]*ms[j]; }
      #pragma unroll
      for (int m = 1; m < 16; m <<= 1){ s += __shfl_xor(s, m); sq += __shfl_xor(sq, m); }
      const float mean = s * (1.f/128.f);
      const float rs = rsqrtf(sq * (1.f/128.f) - mean*mean + 1e-5f);
      bf16x8 o;
      #pragma unroll
      for (int j = 0; j < 8; ++j)
        o[j] = (short)f2bf((ms[j]-mean)*rs*g8[j] + b8[j]);
      *(bf16x8*)&sH[r*128 + (c0g ^ ((r & 7) << 3))] = o;
    }
  }
  __syncthreads();

  // ---- P7: MLP transposed, 4 chunks of 128 hidden; sG single-buffered ----
  f32x4 accO[2][4];   // [out-ch tile][token tile]
  #pragma unroll
  for (int ot = 0; ot < 2; ++ot){
    const f32x4 b2v = *(const f32x4*)(mlp_b2 + (wid*2 + ot)*16 + kg*4);
    #pragma unroll
    for (int tt = 0; tt < 4; ++tt) accO[ot][tt] = b2v;
  }
  #pragma unroll
  for (int c = 0; c < 4; ++c){
    f32x4 t4[2][4];   // [hidden tile][token tile]
    #pragma unroll
    for (int ht = 0; ht < 2; ++ht){
      const f32x4 b1v = *(const f32x4*)(mlp_b1 + c*128 + (wid*2 + ht)*16 + kg*4);
      #pragma unroll
      for (int tt = 0; tt < 4; ++tt) t4[ht][tt] = b1v;
    }
    #pragma unroll
    for (int kk = 0; kk < 4; ++kk){
      bf16x8 aW[2], bL[4];
      const int c0 = kk*32 + kg*8;
      #pragma unroll
      for (int ht = 0; ht < 2; ++ht)
        aW[ht] = *(const bf16x8*)(rep_w1 + (size_t)((kk*32 + c*8 + wid*2 + ht)*64 + lane)*8);
      #pragma unroll
      for (int tt = 0; tt < 4; ++tt){
        const int row = tt*16 + r15;
        bL[tt] = *(const bf16x8*)&sH[row*128 + (c0 ^ ((row & 7) << 3))];
      }
      #pragma unroll
      for (int ht = 0; ht < 2; ++ht)
        #pragma unroll
        for (int tt = 0; tt < 4; ++tt)
          t4[ht][tt] = __builtin_amdgcn_mfma_f32_16x16x32_bf16(aW[ht], bL[tt], t4[ht][tt], 0, 0, 0);
    }
    // sigmoid-GELU -> packed regs
    bf16x4 gp[2][4];
    #pragma unroll
    for (int ht = 0; ht < 2; ++ht)
      #pragma unroll
      for (int tt = 0; tt < 4; ++tt){
        #pragma unroll
        for (int rg = 0; rg < 4; ++rg){
          const float v = t4[ht][tt][rg];
          const float e = __expf(-1.702f * v);
          gp[ht][tt][rg] = (short)f2bf(v * __builtin_amdgcn_rcpf(1.f + e));
        }
      }
    __syncthreads();   // previous chunk's sG reads complete
    #pragma unroll
    for (int ht = 0; ht < 2; ++ht){
      const int colu = (wid*2 + ht)*16 + kg*4;
      #pragma unroll
      for (int tt = 0; tt < 4; ++tt){
        const int row = tt*16 + r15;
        *(bf16x4*)&sG[row*128 + (colu ^ ((row & 7) << 3))] = gp[ht][tt];
      }
    }
    __syncthreads();   // sG ready
    #pragma unroll
    for (int kk = 0; kk < 4; ++kk){
      bf16x8 aW2[2], bG[4];
      const int c0 = kk*32 + kg*8;
      #pragma unroll
      for (int ot = 0; ot < 2; ++ot)
        aW2[ot] = *(const bf16x8*)(rep_w2 + (size_t)(((c*4 + kk)*8 + wid*2 + ot)*64 + lane)*8);
      #pragma unroll
      for (int tt = 0; tt < 4; ++tt){
        const int row = tt*16 + r15;
        bG[tt] = *(const bf16x8*)&sG[row*128 + (c0 ^ ((row & 7) << 3))];
      }
      #pragma unroll
      for (int ot = 0; ot < 2; ++ot)
        #pragma unroll
        for (int tt = 0; tt < 4; ++tt)
          accO[ot][tt] = __builtin_amdgcn_mfma_f32_16x16x32_bf16(aW2[ot], bG[tt], accO[ot][tt], 0, 0, 0);
    }
  }
  __syncthreads();

  // ---- P8: out = msa(stg) + mlp, scattered to image layout ----
  #pragma unroll
  for (int ot = 0; ot < 2; ++ot){
    const int cbase = (wid*2 + ot)*16 + kg*4;
    #pragma unroll
    for (int tt = 0; tt < 4; ++tt){
      const int tok = tt*16 + r15;
      const int pix = ((tok >> 3) * 8 + ihb) * 64 + (tok & 7) * 8 + iwb;
      const f32x4 m4 = *(const f32x4*)&stg[tok*128 + (cbase ^ ((tok & 7) << 2))];
      f32x4 o;
      #pragma unroll
      for (int rg = 0; rg < 4; ++rg) o[rg] = m4[rg] + accO[ot][tt][rg];
      *(f32x4*)(ob + (size_t)pix * 128 + cbase) = o;
    }
  }
}

// ---------------------------------------------------------------------------
// ws layout (bytes): rq 0..98304 | rp ..131072 | r1 ..262144 | r2 ..393216 |
// be ..458752.
// ---------------------------------------------------------------------------
extern "C" void kernel_launch(void* const* d_in, const int* in_sizes, int n_in,
                              void* d_out, int out_size, void* d_ws, size_t ws_size,
                              hipStream_t stream){
  (void)in_sizes; (void)n_in; (void)out_size; (void)ws_size;
  const float* x      = (const float*)d_in[0];
  const float* qkv_w  = (const float*)d_in[1];
  const float* qkv_b  = (const float*)d_in[2];
  const float* proj_w = (const float*)d_in[3];
  const float* proj_b = (const float*)d_in[4];
  const float* tbl    = (const float*)d_in[5];
  const float* ln1_g  = (const float*)d_in[6];
  const float* ln1_b  = (const float*)d_in[7];
  const float* ln2_g  = (const float*)d_in[8];
  const float* ln2_b  = (const float*)d_in[9];
  const float* w1     = (const float*)d_in[10];
  const float* b1     = (const float*)d_in[11];
  const float* w2     = (const float*)d_in[12];
  const float* b2     = (const float*)d_in[13];

  char* ws = (char*)d_ws;
  u16*   rq  = (u16*)ws;
  u16*   rp  = (u16*)(ws + 98304);
  u16*   r1  = (u16*)(ws + 131072);
  u16*   r2  = (u16*)(ws + 262144);
  float* be  = (float*)(ws + 393216);

  hipLaunchKernelGGL(repack_kernel, dim3(256), dim3(256), 0, stream,
                     qkv_w, proj_w, w1, w2, tbl, rq, rp, r1, r2, be);
  hipLaunchKernelGGL(block_kernel, dim3(2048), dim3(256), 0, stream,
                     x, qkv_b, proj_b, ln1_g, ln1_b, ln2_g, ln2_b,
                     rq, rp, r1, r2, b1, b2, be, (float*)d_out);
}

// Round 6
// 98.728 us; speedup vs baseline: 1.8633x; 1.2374x over previous
//
#include <hip/hip_runtime.h>
#include <hip/hip_bf16.h>

typedef __attribute__((ext_vector_type(4))) float f32x4;
typedef __attribute__((ext_vector_type(8))) short bf16x8;
typedef __attribute__((ext_vector_type(4))) short bf16x4;
typedef __attribute__((ext_vector_type(2))) unsigned u32x2;
typedef unsigned short u16;

__device__ __forceinline__ short fbf(float f){   // f32 -> bf16 (RNE); compiler pairs into v_cvt_pk_bf16_f32
  __hip_bfloat16 h = __float2bfloat16(f);
  return *reinterpret_cast<short*>(&h);
}
__device__ __forceinline__ float bf2f(short s){
  return __uint_as_float(((unsigned)(unsigned short)s) << 16);
}

#define LOG2E 1.4426950408889634f

// ---------------------------------------------------------------------------
// K0: repack f32 weights into bf16 MFMA fragment order + expand relative
// bias into MFMA C-fragment layout for S^T = K·Q^T (row=k_token, col=q_token),
// pre-scaled by log2(e) for exp2-domain softmax.
// Fragment (kk, nt, lane, j) holds W[k = kk*32 + (lane>>4)*8 + j][nt*16 + (lane&15)].
// ---------------------------------------------------------------------------
__global__ void repack_kernel(const float* __restrict__ qkv_w, const float* __restrict__ proj_w,
                              const float* __restrict__ w1, const float* __restrict__ w2,
                              const float* __restrict__ tbl,
                              u16* __restrict__ rq, u16* __restrict__ rp,
                              u16* __restrict__ r1, u16* __restrict__ r2,
                              float* __restrict__ be){
  const int i = blockIdx.x * 256 + threadIdx.x;          // 0 .. 65535
  const int j = i & 7, lane = (i >> 3) & 63, f = i >> 9;
  const int kr = (lane >> 4) * 8 + j;                    // k within 32-chunk
  const int c16 = lane & 15;
  if (i < 49152){ int nt = f % 24, kk = f / 24; rq[i] = (u16)fbf(qkv_w[(kk*32 + kr)*384 + nt*16 + c16]); }
  if (i < 16384){ int nt = f & 7,  kk = f >> 3; rp[i] = (u16)fbf(proj_w[(kk*32 + kr)*128 + nt*16 + c16]); }
  if (i < 65536){ int nt = f & 31, kk = f >> 5; r1[i] = (u16)fbf(w1[(kk*32 + kr)*512 + nt*16 + c16]); }
  if (i < 65536){ int nt = f & 7,  kk = f >> 3; r2[i] = (u16)fbf(w2[(kk*32 + kr)*128 + nt*16 + c16]); }
  if (i < 16384){
    int rg = i & 3, ln = (i >> 2) & 63, g = i >> 8;
    int nt = g & 3, mt = (g >> 2) & 3, h = g >> 4;
    int row = mt*16 + (ln >> 4)*4 + rg;   // k_token (C row)
    int col = nt*16 + (ln & 15);          // q_token (C col)
    int rel = ((col >> 3) - (row >> 3) + 7) * 15 + ((col & 7) - (row & 7) + 7);
    be[i] = tbl[rel*4 + h] * LOG2E;
  }
}

// ---------------------------------------------------------------------------
// K1: fully fused Swin block, one workgroup per 64-token window.
// 256 threads (4 waves, wave == head for attn). LDS 48 KB -> 3 blocks/CU.
// msa lives only in LDS (bf16, LN2-input + residual); d_out written once.
// LDS u16 map (regions of 8192 u16 = 16 KB):
//   R0 [0,8192):      sLN -> sQ -> sP(heads 0,1) -> sO -> sG
//   R1 [8192,16384):  sK -> sP(heads 2,3) -> stg (msa bf16)
//   R2 [16384,24576): sV -> sH (LN2 bf16)
// ---------------------------------------------------------------------------
__global__ __launch_bounds__(256, 3)
void block_kernel(const float* __restrict__ x,
                  const float* __restrict__ qkv_b, const float* __restrict__ proj_b,
                  const float* __restrict__ ln1_g, const float* __restrict__ ln1_b,
                  const float* __restrict__ ln2_g, const float* __restrict__ ln2_b,
                  const u16* __restrict__ rep_qkv, const u16* __restrict__ rep_proj,
                  const u16* __restrict__ rep_w1, const u16* __restrict__ rep_w2,
                  const float* __restrict__ mlp_b1, const float* __restrict__ mlp_b2,
                  const float* __restrict__ bias_exp,
                  float* __restrict__ out){
  __shared__ __align__(16) u16 smem[24576];
  u16* sLN = smem;                    // [64][128]
  u16* sQ  = smem;                    // [64 tok][128 d_all]
  u16* sK  = smem + 8192;             // [64 tok][128 d_all]
  u16* sV  = smem + 16384;            // V^T [128 d_all][64 tok]
  u16* sP  = smem;                    // per-head [64 q][64 k] at wid*4096
  u16* sO  = smem;                    // [64 tok][128 ch]
  u16* stg = smem + 8192;             // [64 tok][128 ch] msa bf16
  u16* sH  = smem + 16384;            // [64 tok][128 ch] LN2 bf16
  u16* sG  = smem;                    // [64 tok][128 hid] gelu bf16

  const int tid = threadIdx.x, lane = tid & 63, wid = tid >> 6;
  const int wdw = blockIdx.x;
  const int bb = wdw >> 6, ihb = (wdw >> 3) & 7, iwb = wdw & 7;
  const float* xb = x + (size_t)bb * 4096 * 128;
  float* ob = out + (size_t)bb * 4096 * 128;
  const f32x4 z4 = {0.f, 0.f, 0.f, 0.f};
  const int rb = tid >> 4, cb = tid & 15, c0g = cb * 8;
  const int r15 = lane & 15, kg = lane >> 4;

  // ---- P1: load window + LN1 -> sLN ----
  {
    float g8[8], b8[8];
    *(f32x4*)&g8[0] = *(const f32x4*)(ln1_g + c0g);
    *(f32x4*)&g8[4] = *(const f32x4*)(ln1_g + c0g + 4);
    *(f32x4*)&b8[0] = *(const f32x4*)(ln1_b + c0g);
    *(f32x4*)&b8[4] = *(const f32x4*)(ln1_b + c0g + 4);
    #pragma unroll
    for (int it = 0; it < 4; ++it){
      const int r = it * 16 + rb;
      const int pix = ((r >> 3) * 8 + ihb) * 64 + (r & 7) * 8 + iwb;
      float fl[8];
      *(f32x4*)&fl[0] = *(const f32x4*)(xb + (size_t)pix * 128 + c0g);
      *(f32x4*)&fl[4] = *(const f32x4*)(xb + (size_t)pix * 128 + c0g + 4);
      float s = 0.f, sq = 0.f;
      #pragma unroll
      for (int j = 0; j < 8; ++j){ s += fl[j]; sq += fl[j]*fl[j]; }
      #pragma unroll
      for (int m = 1; m < 16; m <<= 1){ s += __shfl_xor(s, m); sq += __shfl_xor(sq, m); }
      const float mean = s * (1.f/128.f);
      const float rs = __builtin_amdgcn_rsqf(sq * (1.f/128.f) - mean*mean + 1e-5f);
      bf16x8 o;
      #pragma unroll
      for (int j = 0; j < 8; ++j) o[j] = fbf((fl[j]-mean)*rs*g8[j] + b8[j]);
      *(bf16x8*)&sLN[r*128 + (c0g ^ ((r & 7) << 3))] = o;
    }
  }
  __syncthreads();   // B1

  // ---- P2: QKV. Q^T,K^T transposed-GEMM; V normal-GEMM. wave = head ----
  {
    f32x4 aqk[4][4];   // [chtile Q0,Q1,K0,K1][token tile]
    f32x4 av[4][2];    // [token tile][d tile]
    #pragma unroll
    for (int ct = 0; ct < 4; ++ct){
      const f32x4 bq = *(const f32x4*)(qkv_b + wid*96 + ct*16 + kg*4);
      #pragma unroll
      for (int tt = 0; tt < 4; ++tt) aqk[ct][tt] = bq;
    }
    #pragma unroll
    for (int nt = 0; nt < 2; ++nt){
      const float bv = qkv_b[wid*96 + 64 + nt*16 + r15];
      const f32x4 bv4 = {bv, bv, bv, bv};
      #pragma unroll
      for (int mt = 0; mt < 4; ++mt) av[mt][nt] = bv4;
    }
    #pragma unroll
    for (int kk = 0; kk < 4; ++kk){
      bf16x8 L[4], aW[4], bWv[2];
      const int c0 = kk*32 + kg*8;
      #pragma unroll
      for (int t = 0; t < 4; ++t){
        const int row = t*16 + r15;
        L[t] = *(const bf16x8*)&sLN[row*128 + (c0 ^ ((row & 7) << 3))];
      }
      #pragma unroll
      for (int ct = 0; ct < 4; ++ct)
        aW[ct] = *(const bf16x8*)(rep_qkv + (size_t)((kk*24 + wid*6 + ct)*64 + lane)*8);
      #pragma unroll
      for (int nt = 0; nt < 2; ++nt)
        bWv[nt] = *(const bf16x8*)(rep_qkv + (size_t)((kk*24 + wid*6 + 4 + nt)*64 + lane)*8);
      #pragma unroll
      for (int ct = 0; ct < 4; ++ct)
        #pragma unroll
        for (int tt = 0; tt < 4; ++tt)
          aqk[ct][tt] = __builtin_amdgcn_mfma_f32_16x16x32_bf16(aW[ct], L[tt], aqk[ct][tt], 0, 0, 0);
      #pragma unroll
      for (int mt = 0; mt < 4; ++mt)
        #pragma unroll
        for (int nt = 0; nt < 2; ++nt)
          av[mt][nt] = __builtin_amdgcn_mfma_f32_16x16x32_bf16(L[mt], bWv[nt], av[mt][nt], 0, 0, 0);
    }
    __syncthreads();   // B2: sLN dead; sQ may overlay
    // Q pre-scaled by 1/sqrt(HD) * log2(e) for exp2 softmax
    #pragma unroll
    for (int ct = 0; ct < 4; ++ct){
      u16* dst = (ct < 2) ? sQ : sK;
      const float scl = (ct < 2) ? 0.2550348296f : 1.0f;
      const int colu = wid*32 + (ct & 1)*16 + kg*4;
      #pragma unroll
      for (int tt = 0; tt < 4; ++tt){
        const int row = tt*16 + r15;
        bf16x4 pk;
        #pragma unroll
        for (int rg = 0; rg < 4; ++rg) pk[rg] = fbf(aqk[ct][tt][rg] * scl);
        *(bf16x4*)&dst[row*128 + (colu ^ ((row & 7) << 3))] = pk;
      }
    }
    #pragma unroll
    for (int nt = 0; nt < 2; ++nt){
      const int row = wid*32 + nt*16 + r15;       // d_all
      #pragma unroll
      for (int mt = 0; mt < 4; ++mt){
        const int colu = mt*16 + kg*4;            // token
        bf16x4 pk;
        #pragma unroll
        for (int rg = 0; rg < 4; ++rg) pk[rg] = fbf(av[mt][nt][rg]);
        *(bf16x4*)&sV[row*64 + (colu ^ ((row & 7) << 3))] = pk;
      }
    }
  }
  __syncthreads();   // B3

  // ---- P3: S^T = K·Q^T + bias (C-input), softmax over k (exp2 domain) ----
  f32x4 s4[4][4];   // [k tile][q tile]
  {
    bf16x8 aK[4], bQ[4];
    #pragma unroll
    for (int t = 0; t < 4; ++t){
      const int row = t*16 + r15;
      const int off = (wid*32 + kg*8) ^ ((row & 7) << 3);
      aK[t] = *(const bf16x8*)&sK[row*128 + off];
      bQ[t] = *(const bf16x8*)&sQ[row*128 + off];
    }
    #pragma unroll
    for (int mtk = 0; mtk < 4; ++mtk)
      #pragma unroll
      for (int ntq = 0; ntq < 4; ++ntq){
        const f32x4 cb4 = *(const f32x4*)(bias_exp + (size_t)(((wid*4 + mtk)*4 + ntq)*64 + lane)*4);
        s4[mtk][ntq] = __builtin_amdgcn_mfma_f32_16x16x32_bf16(aK[mtk], bQ[ntq], cb4, 0, 0, 0);
      }
  }
  #pragma unroll
  for (int ntq = 0; ntq < 4; ++ntq){
    float mx = s4[0][ntq][0];
    #pragma unroll
    for (int mtk = 0; mtk < 4; ++mtk)
      #pragma unroll
      for (int rg = 0; rg < 4; ++rg) mx = fmaxf(mx, s4[mtk][ntq][rg]);
    mx = fmaxf(mx, __shfl_xor(mx, 16));
    mx = fmaxf(mx, __shfl_xor(mx, 32));
    float sum = 0.f;
    #pragma unroll
    for (int mtk = 0; mtk < 4; ++mtk)
      #pragma unroll
      for (int rg = 0; rg < 4; ++rg){
        const float e = __builtin_amdgcn_exp2f(s4[mtk][ntq][rg] - mx);
        s4[mtk][ntq][rg] = e; sum += e;
      }
    sum += __shfl_xor(sum, 16);
    sum += __shfl_xor(sum, 32);
    const float inv = __builtin_amdgcn_rcpf(sum);
    #pragma unroll
    for (int mtk = 0; mtk < 4; ++mtk)
      #pragma unroll
      for (int rg = 0; rg < 4; ++rg) s4[mtk][ntq][rg] *= inv;
  }
  __syncthreads();   // B4: Q/K dead; sP overlays R0+R1
  #pragma unroll
  for (int ntq = 0; ntq < 4; ++ntq){
    const int row = ntq*16 + r15;                 // q
    #pragma unroll
    for (int mtk = 0; mtk < 4; ++mtk){
      const int colu = mtk*16 + kg*4;             // k local
      bf16x4 pk;
      #pragma unroll
      for (int rg = 0; rg < 4; ++rg) pk[rg] = fbf(s4[mtk][ntq][rg]);
      *(bf16x4*)&sP[wid*4096 + row*64 + (colu ^ ((row & 7) << 3))] = pk;
    }
  }
  __syncthreads();   // B5: P fully written

  // ---- P4: O^T = V^T·P^T -> sO[tok][ch] ----
  {
    f32x4 o4[2][4];   // [d tile][q tile]
    #pragma unroll
    for (int dt = 0; dt < 2; ++dt)
      #pragma unroll
      for (int qt = 0; qt < 4; ++qt) o4[dt][qt] = z4;
    #pragma unroll
    for (int ks = 0; ks < 2; ++ks){
      bf16x8 aV[2], bP[4];
      #pragma unroll
      for (int dt = 0; dt < 2; ++dt){
        const int rowd = wid*32 + dt*16 + r15;
        aV[dt] = *(const bf16x8*)&sV[rowd*64 + ((ks*32 + kg*8) ^ ((rowd & 7) << 3))];
      }
      #pragma unroll
      for (int qt = 0; qt < 4; ++qt){
        const int rowq = qt*16 + r15;
        bP[qt] = *(const bf16x8*)&sP[wid*4096 + rowq*64 + ((ks*32 + kg*8) ^ ((rowq & 7) << 3))];
      }
      #pragma unroll
      for (int dt = 0; dt < 2; ++dt)
        #pragma unroll
        for (int qt = 0; qt < 4; ++qt)
          o4[dt][qt] = __builtin_amdgcn_mfma_f32_16x16x32_bf16(aV[dt], bP[qt], o4[dt][qt], 0, 0, 0);
    }
    __syncthreads();   // B6: P,V dead; sO overlays R0
    #pragma unroll
    for (int dt = 0; dt < 2; ++dt){
      const int dbase = wid*32 + dt*16 + kg*4;
      #pragma unroll
      for (int qt = 0; qt < 4; ++qt){
        const int q = qt*16 + r15;
        bf16x4 pk;
        #pragma unroll
        for (int rg = 0; rg < 4; ++rg) pk[rg] = fbf(o4[dt][qt][rg]);
        *(bf16x4*)&sO[q*128 + (dbase ^ ((q & 7) << 3))] = pk;
      }
    }
  }
  __syncthreads();   // B7: O complete

  // ---- P5: proj^T = Wp^T·O^T; msa = x + proj in regs -> stg (bf16) ----
  {
    f32x4 po[2][4];   // [out-ch tile][token tile]
    #pragma unroll
    for (int ot = 0; ot < 2; ++ot){
      const f32x4 pb4 = *(const f32x4*)(proj_b + (wid*2 + ot)*16 + kg*4);
      #pragma unroll
      for (int tt = 0; tt < 4; ++tt) po[ot][tt] = pb4;
    }
    #pragma unroll
    for (int kk = 0; kk < 4; ++kk){
      bf16x8 aWp[2], bO[4];
      #pragma unroll
      for (int ot = 0; ot < 2; ++ot)
        aWp[ot] = *(const bf16x8*)(rep_proj + (size_t)((kk*8 + wid*2 + ot)*64 + lane)*8);
      #pragma unroll
      for (int tt = 0; tt < 4; ++tt){
        const int row = tt*16 + r15;
        bO[tt] = *(const bf16x8*)&sO[row*128 + ((kk*32 + kg*8) ^ ((row & 7) << 3))];
      }
      #pragma unroll
      for (int ot = 0; ot < 2; ++ot)
        #pragma unroll
        for (int tt = 0; tt < 4; ++tt)
          po[ot][tt] = __builtin_amdgcn_mfma_f32_16x16x32_bf16(aWp[ot], bO[tt], po[ot][tt], 0, 0, 0);
    }
    // residual: reload x in C-fragment layout (L2/L3-hot), msa -> stg bf16
    #pragma unroll
    for (int ot = 0; ot < 2; ++ot){
      const int cbase = (wid*2 + ot)*16 + kg*4;
      #pragma unroll
      for (int tt = 0; tt < 4; ++tt){
        const int tok = tt*16 + r15;
        const int pix = ((tok >> 3) * 8 + ihb) * 64 + (tok & 7) * 8 + iwb;
        const f32x4 xv = *(const f32x4*)(xb + (size_t)pix * 128 + cbase);
        bf16x4 pk;
        #pragma unroll
        for (int rg = 0; rg < 4; ++rg) pk[rg] = fbf(po[ot][tt][rg] + xv[rg]);
        *(bf16x4*)&stg[tok*128 + (cbase ^ ((tok & 7) << 3))] = pk;
      }
    }
  }
  __syncthreads();   // B8: msa(stg) ready

  // ---- P6: LN2(stg) -> sH ----
  {
    float g8[8], b8[8];
    *(f32x4*)&g8[0] = *(const f32x4*)(ln2_g + c0g);
    *(f32x4*)&g8[4] = *(const f32x4*)(ln2_g + c0g + 4);
    *(f32x4*)&b8[0] = *(const f32x4*)(ln2_b + c0g);
    *(f32x4*)&b8[4] = *(const f32x4*)(ln2_b + c0g + 4);
    #pragma unroll
    for (int it = 0; it < 4; ++it){
      const int r = it * 16 + rb;
      bf16x8 m8 = *(const bf16x8*)&stg[r*128 + (c0g ^ ((r & 7) << 3))];
      float fl[8];
      #pragma unroll
      for (int j = 0; j < 8; ++j) fl[j] = bf2f(m8[j]);
      float s = 0.f, sq = 0.f;
      #pragma unroll
      for (int j = 0; j < 8; ++j){ s += fl[j]; sq += fl[j]*fl[j]; }
      #pragma unroll
      for (int m = 1; m < 16; m <<= 1){ s += __shfl_xor(s, m); sq += __shfl_xor(sq, m); }
      const float mean = s * (1.f/128.f);
      const float rs = __builtin_amdgcn_rsqf(sq * (1.f/128.f) - mean*mean + 1e-5f);
      bf16x8 o;
      #pragma unroll
      for (int j = 0; j < 8; ++j) o[j] = fbf((fl[j]-mean)*rs*g8[j] + b8[j]);
      *(bf16x8*)&sH[r*128 + (c0g ^ ((r & 7) << 3))] = o;
    }
  }
  __syncthreads();   // B9

  // ---- P7: MLP transposed, 4 chunks of 128 hidden ----
  f32x4 accO[2][4];   // [out-ch tile][token tile]
  #pragma unroll
  for (int ot = 0; ot < 2; ++ot){
    const f32x4 b2v = *(const f32x4*)(mlp_b2 + (wid*2 + ot)*16 + kg*4);
    #pragma unroll
    for (int tt = 0; tt < 4; ++tt) accO[ot][tt] = b2v;
  }
  #pragma unroll
  for (int c = 0; c < 4; ++c){
    f32x4 t4[2][4];   // [hidden tile][token tile]
    #pragma unroll
    for (int ht = 0; ht < 2; ++ht){
      const f32x4 b1v = *(const f32x4*)(mlp_b1 + c*128 + (wid*2 + ht)*16 + kg*4);
      #pragma unroll
      for (int tt = 0; tt < 4; ++tt) t4[ht][tt] = b1v;
    }
    #pragma unroll
    for (int kk = 0; kk < 4; ++kk){
      bf16x8 aW[2], bL[4];
      const int c0 = kk*32 + kg*8;
      #pragma unroll
      for (int ht = 0; ht < 2; ++ht)
        aW[ht] = *(const bf16x8*)(rep_w1 + (size_t)((kk*32 + c*8 + wid*2 + ht)*64 + lane)*8);
      #pragma unroll
      for (int tt = 0; tt < 4; ++tt){
        const int row = tt*16 + r15;
        bL[tt] = *(const bf16x8*)&sH[row*128 + (c0 ^ ((row & 7) << 3))];
      }
      #pragma unroll
      for (int ht = 0; ht < 2; ++ht)
        #pragma unroll
        for (int tt = 0; tt < 4; ++tt)
          t4[ht][tt] = __builtin_amdgcn_mfma_f32_16x16x32_bf16(aW[ht], bL[tt], t4[ht][tt], 0, 0, 0);
    }
    // sigmoid-GELU (exp2 domain) -> packed regs
    bf16x4 gp[2][4];
    #pragma unroll
    for (int ht = 0; ht < 2; ++ht)
      #pragma unroll
      for (int tt = 0; tt < 4; ++tt){
        #pragma unroll
        for (int rg = 0; rg < 4; ++rg){
          const float v = t4[ht][tt][rg];
          const float e = __builtin_amdgcn_exp2f(-2.4554669f * v);
          gp[ht][tt][rg] = fbf(v * __builtin_amdgcn_rcpf(1.f + e));
        }
      }
    __syncthreads();   // prior chunk's sG reads (and P5's sO reads) complete
    #pragma unroll
    for (int ht = 0; ht < 2; ++ht){
      const int colu = (wid*2 + ht)*16 + kg*4;
      #pragma unroll
      for (int tt = 0; tt < 4; ++tt){
        const int row = tt*16 + r15;
        *(bf16x4*)&sG[row*128 + (colu ^ ((row & 7) << 3))] = gp[ht][tt];
      }
    }
    __syncthreads();   // sG ready
    #pragma unroll
    for (int kk = 0; kk < 4; ++kk){
      bf16x8 aW2[2], bG[4];
      const int c0 = kk*32 + kg*8;
      #pragma unroll
      for (int ot = 0; ot < 2; ++ot)
        aW2[ot] = *(const bf16x8*)(rep_w2 + (size_t)(((c*4 + kk)*8 + wid*2 + ot)*64 + lane)*8);
      #pragma unroll
      for (int tt = 0; tt < 4; ++tt){
        const int row = tt*16 + r15;
        bG[tt] = *(const bf16x8*)&sG[row*128 + (c0 ^ ((row & 7) << 3))];
      }
      #pragma unroll
      for (int ot = 0; ot < 2; ++ot)
        #pragma unroll
        for (int tt = 0; tt < 4; ++tt)
          accO[ot][tt] = __builtin_amdgcn_mfma_f32_16x16x32_bf16(aW2[ot], bG[tt], accO[ot][tt], 0, 0, 0);
    }
  }

  // ---- P8: out = msa(stg bf16) + mlp, scattered to image layout ----
  #pragma unroll
  for (int ot = 0; ot < 2; ++ot){
    const int cbase = (wid*2 + ot)*16 + kg*4;
    #pragma unroll
    for (int tt = 0; tt < 4; ++tt){
      const int tok = tt*16 + r15;
      const int pix = ((tok >> 3) * 8 + ihb) * 64 + (tok & 7) * 8 + iwb;
      bf16x4 m4 = *(const bf16x4*)&stg[tok*128 + (cbase ^ ((tok & 7) << 3))];
      f32x4 o;
      #pragma unroll
      for (int rg = 0; rg < 4; ++rg) o[rg] = bf2f(m4[rg]) + accO[ot][tt][rg];
      *(f32x4*)(ob + (size_t)pix * 128 + cbase) = o;
    }
  }
}

// ---------------------------------------------------------------------------
// ws layout (bytes): rq 0..98304 | rp ..131072 | r1 ..262144 | r2 ..393216 |
// be ..458752.
// ---------------------------------------------------------------------------
extern "C" void kernel_launch(void* const* d_in, const int* in_sizes, int n_in,
                              void* d_out, int out_size, void* d_ws, size_t ws_size,
                              hipStream_t stream){
  (void)in_sizes; (void)n_in; (void)out_size; (void)ws_size;
  const float* x      = (const float*)d_in[0];
  const float* qkv_w  = (const float*)d_in[1];
  const float* qkv_b  = (const float*)d_in[2];
  const float* proj_w = (const float*)d_in[3];
  const float* proj_b = (const float*)d_in[4];
  const float* tbl    = (const float*)d_in[5];
  const float* ln1_g  = (const float*)d_in[6];
  const float* ln1_b  = (const float*)d_in[7];
  const float* ln2_g  = (const float*)d_in[8];
  const float* ln2_b  = (const float*)d_in[9];
  const float* w1     = (const float*)d_in[10];
  const float* b1     = (const float*)d_in[11];
  const float* w2     = (const float*)d_in[12];
  const float* b2     = (const float*)d_in[13];

  char* ws = (char*)d_ws;
  u16*   rq  = (u16*)ws;
  u16*   rp  = (u16*)(ws + 98304);
  u16*   r1  = (u16*)(ws + 131072);
  u16*   r2  = (u16*)(ws + 262144);
  float* be  = (float*)(ws + 393216);

  hipLaunchKernelGGL(repack_kernel, dim3(256), dim3(256), 0, stream,
                     qkv_w, proj_w, w1, w2, tbl, rq, rp, r1, r2, be);
  hipLaunchKernelGGL(block_kernel, dim3(2048), dim3(256), 0, stream,
                     x, qkv_b, proj_b, ln1_g, ln1_b, ln2_g, ln2_b,
                     rq, rp, r1, r2, b1, b2, be, (float*)d_out);
}